// Round 6
// baseline (338.640 us; speedup 1.0000x reference)
//
#include <hip/hip_runtime.h>

typedef __attribute__((ext_vector_type(8))) short short8;
typedef __attribute__((ext_vector_type(4))) float float4v;

__device__ inline float bf2f(ushort u) {
    unsigned v = ((unsigned)u) << 16;
    return __builtin_bit_cast(float, v);
}
__device__ inline ushort f2bf(float f) {
    unsigned u = __builtin_bit_cast(unsigned, f);
    u += 0x7FFFu + ((u >> 16) & 1u);   // RNE
    return (ushort)(u >> 16);
}

// ---------------------------------------------------------------------------
// Kernel 1: hs fp32 -> bf16 [4096][1024]
// ---------------------------------------------------------------------------
__global__ __launch_bounds__(256) void convert_hs(
    const float* __restrict__ hs, ushort* __restrict__ hsb) {
    const size_t idx = ((size_t)blockIdx.x * 256 + threadIdx.x) * 4;
    float4v f = *(const float4v*)(hs + idx);
    union { ushort u[4]; uint2 v; } o;
#pragma unroll
    for (int j = 0; j < 4; ++j) o.u[j] = f2bf(f[j]);
    *(uint2*)(hsb + idx) = o.v;
}

// ---------------------------------------------------------------------------
// Kernel 2: W fp32 [K][N] -> Wt bf16 [N][K] (transpose + downcast)
// ---------------------------------------------------------------------------
__global__ __launch_bounds__(256) void transpose_w(
    const float* __restrict__ Wq, const float* __restrict__ Wv,
    ushort* __restrict__ Wtq, ushort* __restrict__ Wtv) {
    __shared__ ushort tile[64][68];
    const float* W = blockIdx.z ? Wv : Wq;
    ushort* Wt     = blockIdx.z ? Wtv : Wtq;
    const int k0 = blockIdx.y * 64, n0 = blockIdx.x * 64;
    const int tid = threadIdx.x;
    const int rr = tid >> 4;          // 0..15
    const int cc = (tid & 15) * 4;    // 0..60
    union U4 { ushort u[4]; uint2 v; };
#pragma unroll
    for (int i = 0; i < 4; ++i) {
        int row = rr + i * 16;
        float4v f = *(const float4v*)(W + (size_t)(k0 + row) * 1024 + n0 + cc);
        U4 x;
#pragma unroll
        for (int j = 0; j < 4; ++j) x.u[j] = f2bf(f[j]);
        *(uint2*)&tile[row][cc] = x.v;
    }
    __syncthreads();
#pragma unroll
    for (int i = 0; i < 4; ++i) {
        int row = rr + i * 16;        // n within tile
        U4 o;
#pragma unroll
        for (int j = 0; j < 4; ++j) o.u[j] = tile[cc + j][row];
        *(uint2*)(Wt + (size_t)(n0 + row) * 1024 + k0 + cc) = o.v;
    }
}

// ---------------------------------------------------------------------------
// Kernel 3: C = hsb @ Wt^T + b -> [B][H][S][64] bf16 (Q and V).
// 128x128 tile, BK=64, 4 waves 2x2, m93-verified MFMA fragment pattern.
// ---------------------------------------------------------------------------
__global__ __launch_bounds__(256) void qv_gemm(
    const ushort* __restrict__ hsb,                                 // [4096][1024] bf16
    const ushort* __restrict__ Wtq, const ushort* __restrict__ Wtv, // [N][K] bf16
    const float* __restrict__ bq, const float* __restrict__ bv,     // fp32
    ushort* __restrict__ q_ws, ushort* __restrict__ v_ws) {
    __shared__ ushort Al[128][72];
    __shared__ ushort Bl[128][72];
    const ushort* Wt  = blockIdx.z ? Wtv : Wtq;
    const float* bias = blockIdx.z ? bv : bq;
    ushort* out       = blockIdx.z ? v_ws : q_ws;
    const int m0 = blockIdx.y * 128;
    const int n0 = blockIdx.x * 128;
    const int tid = threadIdx.x;
    const int wid = tid >> 6, lane = tid & 63;
    const int quad = lane >> 4, l16 = lane & 15;
    const int wm = (wid >> 1) * 64, wn = (wid & 1) * 64;

    float4v acc[4][4] = {};

    for (int kt = 0; kt < 1024; kt += 64) {
        __syncthreads();
#pragma unroll
        for (int i = 0; i < 4; ++i) {
            int c = tid + i * 256;
            int row = c >> 3, col = (c & 7) * 8;
            *(uint4*)&Al[row][col] = *(const uint4*)(hsb + (size_t)(m0 + row) * 1024 + kt + col);
            *(uint4*)&Bl[row][col] = *(const uint4*)(Wt + (size_t)(n0 + row) * 1024 + kt + col);
        }
        __syncthreads();
#pragma unroll
        for (int ks = 0; ks < 2; ++ks) {
            short8 af[4], bfr[4];
#pragma unroll
            for (int mt = 0; mt < 4; ++mt)
                af[mt] = *(const short8*)&Al[wm + mt * 16 + l16][ks * 32 + quad * 8];
#pragma unroll
            for (int nt = 0; nt < 4; ++nt)
                bfr[nt] = *(const short8*)&Bl[wn + nt * 16 + l16][ks * 32 + quad * 8];
#pragma unroll
            for (int mt = 0; mt < 4; ++mt)
#pragma unroll
                for (int nt = 0; nt < 4; ++nt)
                    acc[mt][nt] = __builtin_amdgcn_mfma_f32_16x16x32_bf16(
                        af[mt], bfr[nt], acc[mt][nt], 0, 0, 0);
        }
    }
    // epilogue: C/D layout col=lane&15, row=quad*4+reg (HW-verified)
#pragma unroll
    for (int mt = 0; mt < 4; ++mt) {
#pragma unroll
        for (int nt = 0; nt < 4; ++nt) {
            int coln = n0 + wn + nt * 16 + l16;
            float bsv = bias[coln];
            int hh = coln >> 6, dd = coln & 63;
#pragma unroll
            for (int reg = 0; reg < 4; ++reg) {
                int r = m0 + wm + mt * 16 + quad * 4 + reg;   // 0..4095
                int bb = r >> 11, s = r & 2047;
                out[(((size_t)bb * 16 + hh) * 2048 + s) * 64 + dd] =
                    f2bf(acc[mt][nt][reg] + bsv);
            }
        }
    }
}

// ---------------------------------------------------------------------------
// Kernel 4: sparse strided attention, one wave per query row. fp32 output.
// keys: window j=i-s, s in [0,min(i,127)]; strided j=i-128k, k in [1,i/128].
// Masked keys contribute exp(~-1250)=0 exactly in fp32 -> skipping is exact.
// ---------------------------------------------------------------------------
__global__ __launch_bounds__(256) void attn_simple(
    const ushort* __restrict__ q_ws, const ushort* __restrict__ v_ws,
    const float* __restrict__ amask, float* __restrict__ out) {
    __shared__ float sc[4][192];
    const int h = blockIdx.y, b = blockIdx.z;
    const int wid = threadIdx.x >> 6, lane = threadIdx.x & 63;
    const int i = blockIdx.x * 4 + wid;                  // query row
    const size_t base = ((size_t)b * 16 + h) * 2048 * 64;
    const float* am = amask + (size_t)b * 2048;

    // q row -> registers (fp32)
    float qr[64];
#pragma unroll
    for (int d0 = 0; d0 < 64; d0 += 8) {
        union { uint4 v; ushort u[8]; } t;
        t.v = *(const uint4*)(q_ws + base + (size_t)i * 64 + d0);
#pragma unroll
        for (int j = 0; j < 8; ++j) qr[d0 + j] = bf2f(t.u[j]);
    }

    float myscore[3];
    int   myj[3];
#pragma unroll
    for (int bidx = 0; bidx < 3; ++bidx) {
        int s = lane + bidx * 64;
        int j = -1;
        if (s < 128) { if (s <= i) j = i - s; }
        else { int k = s - 127; if (k <= (i >> 7)) j = i - (k << 7); }
        myj[bidx] = j;
        float scv = -INFINITY;
        if (j >= 0) {
            float dot = 0.f;
            const ushort* kr = q_ws + base + (size_t)j * 64;
#pragma unroll
            for (int d0 = 0; d0 < 64; d0 += 8) {
                union { uint4 v; ushort u[8]; } t;
                t.v = *(const uint4*)(kr + d0);
#pragma unroll
                for (int jj = 0; jj < 8; ++jj) dot += qr[d0 + jj] * bf2f(t.u[jj]);
            }
            scv = dot * 0.125f + am[j];
        }
        myscore[bidx] = scv;
    }
    float m = fmaxf(fmaxf(myscore[0], myscore[1]), myscore[2]);
#pragma unroll
    for (int off = 1; off < 64; off <<= 1) m = fmaxf(m, __shfl_xor(m, off));
    float e[3], sum = 0.f;
#pragma unroll
    for (int bidx = 0; bidx < 3; ++bidx) {
        e[bidx] = (myj[bidx] >= 0) ? __expf(myscore[bidx] - m) : 0.f;
        sum += e[bidx];
    }
#pragma unroll
    for (int off = 1; off < 64; off <<= 1) sum += __shfl_xor(sum, off);
    float rden = 1.f / sum;
#pragma unroll
    for (int bidx = 0; bidx < 3; ++bidx)
        sc[wid][lane + bidx * 64] = e[bidx] * rden;
    __syncthreads();

    // ctx: lane owns output dim d = lane
    float ctxd = 0.f;
    const ushort* vb = v_ws + base;
    int nw = (i < 127) ? i : 127;
    for (int s = 0; s <= nw; ++s)
        ctxd += sc[wid][s] * bf2f(vb[(size_t)(i - s) * 64 + lane]);
    int nk = i >> 7;
    for (int k = 1; k <= nk; ++k)
        ctxd += sc[wid][127 + k] * bf2f(vb[(size_t)(i - (k << 7)) * 64 + lane]);

    // fp32 output, [b][s][h*64+d]
    out[((size_t)b * 2048 + i) * 1024 + h * 64 + lane] = ctxd;
}

// ---------------------------------------------------------------------------
extern "C" void kernel_launch(void* const* d_in, const int* in_sizes, int n_in,
                              void* d_out, int out_size, void* d_ws, size_t ws_size,
                              hipStream_t stream) {
    // Identify inputs by element count (robust to ordering):
    int ihs = -1, iam = -1, iw1 = -1, iw2 = -1, ib1 = -1, ib2 = -1;
    for (int i = 0; i < n_in; ++i) {
        int s = in_sizes[i];
        if      (s == 4194304) { if (ihs < 0) ihs = i; }
        else if (s == 4096)    { if (iam < 0) iam = i; }
        else if (s == 1048576) { if (iw1 < 0) iw1 = i; else if (iw2 < 0) iw2 = i; }
        else if (s == 1024)    { if (ib1 < 0) ib1 = i; else if (ib2 < 0) ib2 = i; }
    }
    if (ihs < 0) ihs = 0; if (iam < 0) iam = 1;
    if (iw1 < 0) iw1 = 2; if (ib1 < 0) ib1 = 3;
    if (iw2 < 0) iw2 = 4; if (ib2 < 0) ib2 = 5;

    const float* hs    = (const float*)d_in[ihs];
    const float* amask = (const float*)d_in[iam];
    const float* Wq    = (const float*)d_in[iw1];
    const float* bq    = (const float*)d_in[ib1];
    const float* Wv    = (const float*)d_in[iw2];
    const float* bv    = (const float*)d_in[ib2];
    float* out = (float*)d_out;                    // fp32 output, per reference

    char* ws = (char*)d_ws;
    ushort* Wtq  = (ushort*)(ws);                          // 2 MB
    ushort* Wtv  = (ushort*)(ws + (1u << 21));             // 2 MB
    ushort* hsb  = (ushort*)(ws + (2u << 21));             // 8 MB
    ushort* q_ws = (ushort*)(ws + (2u << 21) + (1u << 23));            // 8 MB
    ushort* v_ws = (ushort*)(ws + (2u << 21) + (2u << 23));            // 8 MB

    convert_hs<<<4096, 256, 0, stream>>>(hs, hsb);
    transpose_w<<<dim3(16, 16, 2), 256, 0, stream>>>(Wq, Wv, Wtq, Wtv);
    qv_gemm<<<dim3(8, 32, 2), 256, 0, stream>>>(hsb, Wtq, Wtv, bq, bv, q_ws, v_ws);
    attn_simple<<<dim3(512, 16, 2), 256, 0, stream>>>(q_ws, v_ws, amask, out);
}

// Round 7
// 182.271 us; speedup vs baseline: 1.8579x; 1.8579x over previous
//
#include <hip/hip_runtime.h>

typedef __attribute__((ext_vector_type(8))) short short8;
typedef __attribute__((ext_vector_type(4))) float float4v;

__device__ inline float bf2f(ushort u) {
    unsigned v = ((unsigned)u) << 16;
    return __builtin_bit_cast(float, v);
}
__device__ inline ushort f2bf(float f) {
    unsigned u = __builtin_bit_cast(unsigned, f);
    u += 0x7FFFu + ((u >> 16) & 1u);   // RNE
    return (ushort)(u >> 16);
}

// ---------------------------------------------------------------------------
// Kernel 1: hs fp32 -> bf16 [4096][1024]
// ---------------------------------------------------------------------------
__global__ __launch_bounds__(256) void convert_hs(
    const float* __restrict__ hs, ushort* __restrict__ hsb) {
    const size_t idx = ((size_t)blockIdx.x * 256 + threadIdx.x) * 4;
    float4v f = *(const float4v*)(hs + idx);
    union { ushort u[4]; uint2 v; } o;
#pragma unroll
    for (int j = 0; j < 4; ++j) o.u[j] = f2bf(f[j]);
    *(uint2*)(hsb + idx) = o.v;
}

// ---------------------------------------------------------------------------
// Kernel 2: W fp32 [K][N] -> Wt bf16 [N][K] (transpose + downcast)
// ---------------------------------------------------------------------------
__global__ __launch_bounds__(256) void transpose_w(
    const float* __restrict__ Wq, const float* __restrict__ Wv,
    ushort* __restrict__ Wtq, ushort* __restrict__ Wtv) {
    __shared__ ushort tile[64][68];
    const float* W = blockIdx.z ? Wv : Wq;
    ushort* Wt     = blockIdx.z ? Wtv : Wtq;
    const int k0 = blockIdx.y * 64, n0 = blockIdx.x * 64;
    const int tid = threadIdx.x;
    const int rr = tid >> 4;          // 0..15
    const int cc = (tid & 15) * 4;    // 0..60
    union U4 { ushort u[4]; uint2 v; };
#pragma unroll
    for (int i = 0; i < 4; ++i) {
        int row = rr + i * 16;
        float4v f = *(const float4v*)(W + (size_t)(k0 + row) * 1024 + n0 + cc);
        U4 x;
#pragma unroll
        for (int j = 0; j < 4; ++j) x.u[j] = f2bf(f[j]);
        *(uint2*)&tile[row][cc] = x.v;
    }
    __syncthreads();
#pragma unroll
    for (int i = 0; i < 4; ++i) {
        int row = rr + i * 16;        // n within tile
        U4 o;
#pragma unroll
        for (int j = 0; j < 4; ++j) o.u[j] = tile[cc + j][row];
        *(uint2*)(Wt + (size_t)(n0 + row) * 1024 + k0 + cc) = o.v;
    }
}

// ---------------------------------------------------------------------------
// Kernel 3: C = hsb @ Wt^T + b -> [B][H][S][64] bf16 (Q and V).
// 128x128 tile, BK=64, 4 waves 2x2.  (HW-validated this round.)
// ---------------------------------------------------------------------------
__global__ __launch_bounds__(256) void qv_gemm(
    const ushort* __restrict__ hsb,                                 // [4096][1024] bf16
    const ushort* __restrict__ Wtq, const ushort* __restrict__ Wtv, // [N][K] bf16
    const float* __restrict__ bq, const float* __restrict__ bv,     // fp32
    ushort* __restrict__ q_ws, ushort* __restrict__ v_ws) {
    __shared__ ushort Al[128][72];
    __shared__ ushort Bl[128][72];
    const ushort* Wt  = blockIdx.z ? Wtv : Wtq;
    const float* bias = blockIdx.z ? bv : bq;
    ushort* out       = blockIdx.z ? v_ws : q_ws;
    const int m0 = blockIdx.y * 128;
    const int n0 = blockIdx.x * 128;
    const int tid = threadIdx.x;
    const int wid = tid >> 6, lane = tid & 63;
    const int quad = lane >> 4, l16 = lane & 15;
    const int wm = (wid >> 1) * 64, wn = (wid & 1) * 64;

    float4v acc[4][4] = {};

    for (int kt = 0; kt < 1024; kt += 64) {
        __syncthreads();
#pragma unroll
        for (int i = 0; i < 4; ++i) {
            int c = tid + i * 256;
            int row = c >> 3, col = (c & 7) * 8;
            *(uint4*)&Al[row][col] = *(const uint4*)(hsb + (size_t)(m0 + row) * 1024 + kt + col);
            *(uint4*)&Bl[row][col] = *(const uint4*)(Wt + (size_t)(n0 + row) * 1024 + kt + col);
        }
        __syncthreads();
#pragma unroll
        for (int ks = 0; ks < 2; ++ks) {
            short8 af[4], bfr[4];
#pragma unroll
            for (int mt = 0; mt < 4; ++mt)
                af[mt] = *(const short8*)&Al[wm + mt * 16 + l16][ks * 32 + quad * 8];
#pragma unroll
            for (int nt = 0; nt < 4; ++nt)
                bfr[nt] = *(const short8*)&Bl[wn + nt * 16 + l16][ks * 32 + quad * 8];
#pragma unroll
            for (int mt = 0; mt < 4; ++mt)
#pragma unroll
                for (int nt = 0; nt < 4; ++nt)
                    acc[mt][nt] = __builtin_amdgcn_mfma_f32_16x16x32_bf16(
                        af[mt], bfr[nt], acc[mt][nt], 0, 0, 0);
        }
    }
#pragma unroll
    for (int mt = 0; mt < 4; ++mt) {
#pragma unroll
        for (int nt = 0; nt < 4; ++nt) {
            int coln = n0 + wn + nt * 16 + l16;
            float bsv = bias[coln];
            int hh = coln >> 6, dd = coln & 63;
#pragma unroll
            for (int reg = 0; reg < 4; ++reg) {
                int r = m0 + wm + mt * 16 + quad * 4 + reg;   // 0..4095
                int bb = r >> 11, s = r & 2047;
                out[(((size_t)bb * 16 + hh) * 2048 + s) * 64 + dd] =
                    f2bf(acc[mt][nt][reg] + bsv);
            }
        }
    }
}

// ---------------------------------------------------------------------------
// Kernel 4: MFMA fused sparse attention, per (b,h,row-tile t). fp32 output.
// Dense band = col tiles t-1,t with mask rr<=c<=rr+128; strided singletons
// j=128k+rr for k<=t-2 on VALU. Masked keys excluded (exp underflow = exact).
// ---------------------------------------------------------------------------
__global__ __launch_bounds__(256) void attn(
    const ushort* __restrict__ q_ws, const ushort* __restrict__ v_ws,
    const float* __restrict__ amask, float* __restrict__ out) {
    const int t = blockIdx.x, h = blockIdx.y, b = blockIdx.z;

    __shared__ ushort Kw[256][72];    // window rows (keys); upper 128 = Q tile t
    __shared__ ushort Vt[64][264];    // V window transposed [d][j]
    __shared__ ushort Pl[128][264];   // probs bf16; later reused as float ctx_part[128][68]
    __shared__ float  Sstr[128][16];  // strided scores -> strided probs
    __shared__ float  am[2048];       // attention_mask row for this b

    const int tid = threadIdx.x;
    const int wid = tid >> 6, lane = tid & 63;
    const int quad = lane >> 4, l16 = lane & 15;
    const int r0 = wid * 32;                 // wave's row base within tile
    const size_t qbase = ((size_t)b * 16 + h) * 2048 * 64;
    const int base_row = (t - 1) * 128;
    const int nk = (t >= 2) ? (t - 1) : 0;   // # strided singleton cols per row

    // ---- stage ----
    *(float4v*)&am[tid * 8]     = *(const float4v*)(amask + (size_t)b * 2048 + tid * 8);
    *(float4v*)&am[tid * 8 + 4] = *(const float4v*)(amask + (size_t)b * 2048 + tid * 8 + 4);
#pragma unroll
    for (int i = 0; i < 8; ++i) {
        int c = tid + i * 256;
        int row = c >> 3, col = (c & 7) * 8;
        int jg = base_row + row; if (jg < 0) jg = 0;   // t=0 lower half: masked anyway
        *(uint4*)&Kw[row][col] = *(const uint4*)(q_ws + qbase + (size_t)jg * 64 + col);
    }
    {
        int jg = base_row + tid; if (jg < 0) jg = 0;
        const ushort* src = v_ws + qbase + (size_t)jg * 64;
#pragma unroll
        for (int d = 0; d < 64; d += 8) {
            union { uint4 v; ushort u[8]; } tmp;
            tmp.v = *(const uint4*)(src + d);
#pragma unroll
            for (int j = 0; j < 8; ++j) Vt[d + j][tid] = tmp.u[j];
        }
    }
    __syncthreads();

    // ---- QK^T dense band: wave computes rows [r0,r0+32) x 256 cols ----
    float4v sacc[2][16] = {};
#pragma unroll
    for (int ks = 0; ks < 2; ++ks) {
        short8 af[2];
#pragma unroll
        for (int mt = 0; mt < 2; ++mt)
            af[mt] = *(const short8*)&Kw[128 + r0 + mt * 16 + l16][ks * 32 + quad * 8];
#pragma unroll
        for (int nt = 0; nt < 16; ++nt) {
            short8 bfr = *(const short8*)&Kw[nt * 16 + l16][ks * 32 + quad * 8];
#pragma unroll
            for (int mt = 0; mt < 2; ++mt)
                sacc[mt][nt] = __builtin_amdgcn_mfma_f32_16x16x32_bf16(
                    af[mt], bfr, sacc[mt][nt], 0, 0, 0);
        }
    }

    // ---- strided scores (VALU): 2 lanes per row, 32-d halves ----
    const int sr = r0 + (lane >> 1);         // row 0..127
    const int dh = (lane & 1) * 32;
    if (nk > 0) {
        float qv[32];
#pragma unroll
        for (int d = 0; d < 32; d += 8) {
            union { uint4 v; ushort u[8]; } tmp;
            tmp.v = *(const uint4*)&Kw[128 + sr][dh + d];
#pragma unroll
            for (int j = 0; j < 8; ++j) qv[d + j] = bf2f(tmp.u[j]);
        }
        for (int k = 0; k < nk; ++k) {
            const ushort* kr = q_ws + qbase + (size_t)(k * 128 + sr) * 64 + dh;
            float p = 0.f;
#pragma unroll
            for (int d = 0; d < 32; d += 8) {
                union { uint4 v; ushort u[8]; } tmp;
                tmp.v = *(const uint4*)(kr + d);
#pragma unroll
                for (int jj = 0; jj < 8; ++jj) p += qv[d + jj] * bf2f(tmp.u[jj]);
            }
            p += __shfl_xor(p, 1);
            if ((lane & 1) == 0)
                Sstr[sr][k] = p * 0.125f + am[k * 128 + sr];
        }
    }
    __syncthreads();

    // ---- softmax per row (rows owned by this wave), write P (bf16) ----
#pragma unroll
    for (int mt = 0; mt < 2; ++mt) {
#pragma unroll
        for (int reg = 0; reg < 4; ++reg) {
            int rr = r0 + mt * 16 + quad * 4 + reg;      // row in tile
            float sv[16];
#pragma unroll
            for (int nt = 0; nt < 16; ++nt) {
                int c = nt * 16 + l16;
                bool allowed = (c >= rr) && (c <= rr + 128) && (t > 0 || c >= 128);
                sv[nt] = allowed
                    ? sacc[mt][nt][reg] * 0.125f + am[base_row + c]
                    : -INFINITY;
            }
            float m = -INFINITY;
#pragma unroll
            for (int nt = 0; nt < 16; ++nt) m = fmaxf(m, sv[nt]);
#pragma unroll
            for (int off = 1; off < 16; off <<= 1) m = fmaxf(m, __shfl_xor(m, off));
            for (int k = 0; k < nk; ++k) m = fmaxf(m, Sstr[rr][k]);

            float sum = 0.f;
#pragma unroll
            for (int nt = 0; nt < 16; ++nt) {
                float e = (sv[nt] == -INFINITY) ? 0.f : __expf(sv[nt] - m);
                sv[nt] = e; sum += e;
            }
#pragma unroll
            for (int off = 1; off < 16; off <<= 1) sum += __shfl_xor(sum, off);
            for (int k = 0; k < nk; ++k) sum += __expf(Sstr[rr][k] - m);
            float rden = 1.f / sum;
#pragma unroll
            for (int nt = 0; nt < 16; ++nt)
                Pl[rr][nt * 16 + l16] = f2bf(sv[nt] * rden);
            if (l16 < nk)
                Sstr[rr][l16] = __expf(Sstr[rr][l16] - m) * rden;
        }
    }
    __syncthreads();

    // ---- PV dense: rows [r0,r0+32) x 64 d, K=256 ----
    float4v cacc[2][4] = {};
#pragma unroll
    for (int ks = 0; ks < 8; ++ks) {
        short8 af[2], bfr[4];
#pragma unroll
        for (int mt = 0; mt < 2; ++mt)
            af[mt] = *(const short8*)&Pl[r0 + mt * 16 + l16][ks * 32 + quad * 8];
#pragma unroll
        for (int nt = 0; nt < 4; ++nt)
            bfr[nt] = *(const short8*)&Vt[nt * 16 + l16][ks * 32 + quad * 8];
#pragma unroll
        for (int mt = 0; mt < 2; ++mt)
#pragma unroll
            for (int nt = 0; nt < 4; ++nt)
                cacc[mt][nt] = __builtin_amdgcn_mfma_f32_16x16x32_bf16(
                    af[mt], bfr[nt], cacc[mt][nt], 0, 0, 0);
    }
    __syncthreads();   // all Pl reads done; region reused as float ctx_part

    // ---- strided PV (VALU) into ctx_part ----
    float* ctxp = (float*)&Pl[0][0];          // [128][68] fp32
    {
        float acc32[32] = {};
        for (int k = 0; k < nk; ++k) {
            float p = Sstr[sr][k];
            const ushort* vr = v_ws + qbase + (size_t)(k * 128 + sr) * 64 + dh;
#pragma unroll
            for (int d = 0; d < 32; d += 8) {
                union { uint4 v; ushort u[8]; } tmp;
                tmp.v = *(const uint4*)(vr + d);
#pragma unroll
                for (int j = 0; j < 8; ++j) acc32[d + j] += p * bf2f(tmp.u[j]);
            }
        }
#pragma unroll
        for (int d = 0; d < 32; d += 4)
            *(float4v*)&ctxp[sr * 68 + dh + d] = *(const float4v*)&acc32[d];
    }
    __syncthreads();

    // ---- epilogue: out[b][s][h*64+d], fp32 ----
    const size_t obase = ((size_t)b * 2048 + (size_t)t * 128) * 1024 + (size_t)h * 64;
#pragma unroll
    for (int mt = 0; mt < 2; ++mt)
#pragma unroll
        for (int nt = 0; nt < 4; ++nt)
#pragma unroll
            for (int reg = 0; reg < 4; ++reg) {
                int rr = r0 + mt * 16 + quad * 4 + reg;
                int d = nt * 16 + l16;
                out[obase + (size_t)rr * 1024 + d] =
                    cacc[mt][nt][reg] + ctxp[rr * 68 + d];
            }
}

// ---------------------------------------------------------------------------
extern "C" void kernel_launch(void* const* d_in, const int* in_sizes, int n_in,
                              void* d_out, int out_size, void* d_ws, size_t ws_size,
                              hipStream_t stream) {
    int ihs = -1, iam = -1, iw1 = -1, iw2 = -1, ib1 = -1, ib2 = -1;
    for (int i = 0; i < n_in; ++i) {
        int s = in_sizes[i];
        if      (s == 4194304) { if (ihs < 0) ihs = i; }
        else if (s == 4096)    { if (iam < 0) iam = i; }
        else if (s == 1048576) { if (iw1 < 0) iw1 = i; else if (iw2 < 0) iw2 = i; }
        else if (s == 1024)    { if (ib1 < 0) ib1 = i; else if (ib2 < 0) ib2 = i; }
    }
    if (ihs < 0) ihs = 0; if (iam < 0) iam = 1;
    if (iw1 < 0) iw1 = 2; if (ib1 < 0) ib1 = 3;
    if (iw2 < 0) iw2 = 4; if (ib2 < 0) ib2 = 5;

    const float* hs    = (const float*)d_in[ihs];
    const float* amask = (const float*)d_in[iam];
    const float* Wq    = (const float*)d_in[iw1];
    const float* bq    = (const float*)d_in[ib1];
    const float* Wv    = (const float*)d_in[iw2];
    const float* bv    = (const float*)d_in[ib2];
    float* out = (float*)d_out;                    // fp32 output

    char* ws = (char*)d_ws;
    ushort* Wtq  = (ushort*)(ws);                          // 2 MB
    ushort* Wtv  = (ushort*)(ws + (1u << 21));             // 2 MB
    ushort* hsb  = (ushort*)(ws + (2u << 21));             // 8 MB
    ushort* q_ws = (ushort*)(ws + (2u << 21) + (1u << 23));   // 8 MB
    ushort* v_ws = (ushort*)(ws + (2u << 21) + (2u << 23));   // 8 MB

    convert_hs<<<4096, 256, 0, stream>>>(hs, hsb);
    transpose_w<<<dim3(16, 16, 2), 256, 0, stream>>>(Wq, Wv, Wtq, Wtv);
    qv_gemm<<<dim3(8, 32, 2), 256, 0, stream>>>(hsb, Wtq, Wtv, bq, bv, q_ws, v_ws);
    attn<<<dim3(16, 16, 2), 256, 0, stream>>>(q_ws, v_ws, amask, out);
}

// Round 8
// 157.504 us; speedup vs baseline: 2.1500x; 1.1572x over previous
//
#include <hip/hip_runtime.h>

typedef __attribute__((ext_vector_type(8))) short short8;
typedef __attribute__((ext_vector_type(4))) float float4v;

__device__ inline float bf2f(ushort u) {
    unsigned v = ((unsigned)u) << 16;
    return __builtin_bit_cast(float, v);
}
__device__ inline ushort f2bf(float f) {
    unsigned u = __builtin_bit_cast(unsigned, f);
    u += 0x7FFFu + ((u >> 16) & 1u);   // RNE
    return (ushort)(u >> 16);
}

// ---------------------------------------------------------------------------
// Kernel 1: W fp32 [K][N] -> Wt bf16 [N][K] (transpose + downcast)
// ---------------------------------------------------------------------------
__global__ __launch_bounds__(256) void transpose_w(
    const float* __restrict__ Wq, const float* __restrict__ Wv,
    ushort* __restrict__ Wtq, ushort* __restrict__ Wtv) {
    __shared__ ushort tile[64][68];
    const float* W = blockIdx.z ? Wv : Wq;
    ushort* Wt     = blockIdx.z ? Wtv : Wtq;
    const int k0 = blockIdx.y * 64, n0 = blockIdx.x * 64;
    const int tid = threadIdx.x;
    const int rr = tid >> 4;          // 0..15
    const int cc = (tid & 15) * 4;    // 0..60
    union U4 { ushort u[4]; uint2 v; };
#pragma unroll
    for (int i = 0; i < 4; ++i) {
        int row = rr + i * 16;
        float4v f = *(const float4v*)(W + (size_t)(k0 + row) * 1024 + n0 + cc);
        U4 x;
#pragma unroll
        for (int j = 0; j < 4; ++j) x.u[j] = f2bf(f[j]);
        *(uint2*)&tile[row][cc] = x.v;
    }
    __syncthreads();
#pragma unroll
    for (int i = 0; i < 4; ++i) {
        int row = rr + i * 16;        // n within tile
        U4 o;
#pragma unroll
        for (int j = 0; j < 4; ++j) o.u[j] = tile[cc + j][row];
        *(uint2*)(Wt + (size_t)(n0 + row) * 1024 + k0 + cc) = o.v;
    }
}

// ---------------------------------------------------------------------------
// Kernel 2: C = hs @ W + b -> [B][H][S][64] bf16. hs fp32 converted inline
// during A-staging (bit-validated in R2/R4). 128x128 tile, BK=64.
// ---------------------------------------------------------------------------
__global__ __launch_bounds__(256) void qv_gemm(
    const float* __restrict__ hs,                                   // [4096][1024] fp32
    const ushort* __restrict__ Wtq, const ushort* __restrict__ Wtv, // [N][K] bf16
    const float* __restrict__ bq, const float* __restrict__ bv,     // fp32
    ushort* __restrict__ q_ws, ushort* __restrict__ v_ws) {
    __shared__ ushort Al[128][72];
    __shared__ ushort Bl[128][72];
    const ushort* Wt  = blockIdx.z ? Wtv : Wtq;
    const float* bias = blockIdx.z ? bv : bq;
    ushort* out       = blockIdx.z ? v_ws : q_ws;
    const int m0 = blockIdx.y * 128;
    const int n0 = blockIdx.x * 128;
    const int tid = threadIdx.x;
    const int wid = tid >> 6, lane = tid & 63;
    const int quad = lane >> 4, l16 = lane & 15;
    const int wm = (wid >> 1) * 64, wn = (wid & 1) * 64;

    float4v acc[4][4] = {};

    for (int kt = 0; kt < 1024; kt += 64) {
        __syncthreads();
#pragma unroll
        for (int i = 0; i < 4; ++i) {
            int c = tid + i * 256;
            int row = c >> 3, col = (c & 7) * 8;
            const float* src = hs + (size_t)(m0 + row) * 1024 + kt + col;
            float4v f0 = *(const float4v*)(src);
            float4v f1 = *(const float4v*)(src + 4);
            union { ushort u[8]; uint4 v; } pk;
#pragma unroll
            for (int j = 0; j < 4; ++j) { pk.u[j] = f2bf(f0[j]); pk.u[4 + j] = f2bf(f1[j]); }
            *(uint4*)&Al[row][col] = pk.v;
            *(uint4*)&Bl[row][col] = *(const uint4*)(Wt + (size_t)(n0 + row) * 1024 + kt + col);
        }
        __syncthreads();
#pragma unroll
        for (int ks = 0; ks < 2; ++ks) {
            short8 af[4], bfr[4];
#pragma unroll
            for (int mt = 0; mt < 4; ++mt)
                af[mt] = *(const short8*)&Al[wm + mt * 16 + l16][ks * 32 + quad * 8];
#pragma unroll
            for (int nt = 0; nt < 4; ++nt)
                bfr[nt] = *(const short8*)&Bl[wn + nt * 16 + l16][ks * 32 + quad * 8];
#pragma unroll
            for (int mt = 0; mt < 4; ++mt)
#pragma unroll
                for (int nt = 0; nt < 4; ++nt)
                    acc[mt][nt] = __builtin_amdgcn_mfma_f32_16x16x32_bf16(
                        af[mt], bfr[nt], acc[mt][nt], 0, 0, 0);
        }
    }
#pragma unroll
    for (int mt = 0; mt < 4; ++mt) {
#pragma unroll
        for (int nt = 0; nt < 4; ++nt) {
            int coln = n0 + wn + nt * 16 + l16;
            float bsv = bias[coln];
            int hh = coln >> 6, dd = coln & 63;
#pragma unroll
            for (int reg = 0; reg < 4; ++reg) {
                int r = m0 + wm + mt * 16 + quad * 4 + reg;   // 0..4095
                int bb = r >> 11, s = r & 2047;
                out[(((size_t)bb * 16 + hh) * 2048 + s) * 64 + dd] =
                    f2bf(acc[mt][nt][reg] + bsv);
            }
        }
    }
}

// ---------------------------------------------------------------------------
// Kernel 3: MFMA fused sparse attention, 512 threads (8 waves), per
// (b,h,row-tile t). Each wave owns one 16-row M-tile. fp32 output.
// ---------------------------------------------------------------------------
__global__ __launch_bounds__(512) void attn(
    const ushort* __restrict__ q_ws, const ushort* __restrict__ v_ws,
    const float* __restrict__ amask, float* __restrict__ out) {
    const int t = blockIdx.x, h = blockIdx.y, b = blockIdx.z;

    __shared__ ushort Kw[256][72];    // window rows; upper 128 = Q tile t
    __shared__ ushort Vt[64][266];    // V window transposed [d][j] (odd dword stride)
    __shared__ ushort Pl[128][266];   // probs bf16; later float ctx_part[128][68]
    __shared__ float  Sstr[128][17];  // strided scores -> probs (odd dword stride)
    __shared__ float  am[2048];       // attention_mask row for this b

    const int tid = threadIdx.x;      // 0..511
    const int wid = tid >> 6, lane = tid & 63;
    const int quad = lane >> 4, l16 = lane & 15;
    const int r0 = wid * 16;          // wave's 16-row M-tile base
    const size_t qbase = ((size_t)b * 16 + h) * 2048 * 64;
    const int base_row = (t - 1) * 128;
    const int nk = (t >= 2) ? (t - 1) : 0;   // strided keys per row

    // ---- stage ----
    *(float4v*)&am[tid * 4] = *(const float4v*)(amask + (size_t)b * 2048 + tid * 4);
#pragma unroll
    for (int i = 0; i < 4; ++i) {
        int c = tid + i * 512;
        int row = c >> 3, col = (c & 7) * 8;
        int jg = base_row + row; if (jg < 0) jg = 0;   // t=0 lower half masked anyway
        *(uint4*)&Kw[row][col] = *(const uint4*)(q_ws + qbase + (size_t)jg * 64 + col);
    }
    {   // Vt: wave-contiguous j, one 32-d half per thread-half (2-way only)
        int j = tid & 255, dh0 = (tid >> 8) * 32;
        int jg = base_row + j; if (jg < 0) jg = 0;
        const ushort* src = v_ws + qbase + (size_t)jg * 64 + dh0;
#pragma unroll
        for (int d = 0; d < 32; d += 8) {
            union { uint4 v; ushort u[8]; } tmp;
            tmp.v = *(const uint4*)(src + d);
#pragma unroll
            for (int jj = 0; jj < 8; ++jj) Vt[dh0 + d + jj][j] = tmp.u[jj];
        }
    }
    __syncthreads();

    // ---- QK^T dense band: wave w -> rows [r0,r0+16) x 256 cols ----
    float4v sacc[16] = {};
#pragma unroll
    for (int ks = 0; ks < 2; ++ks) {
        short8 af = *(const short8*)&Kw[128 + r0 + l16][ks * 32 + quad * 8];
#pragma unroll
        for (int nt = 0; nt < 16; ++nt) {
            short8 bfr = *(const short8*)&Kw[nt * 16 + l16][ks * 32 + quad * 8];
            sacc[nt] = __builtin_amdgcn_mfma_f32_16x16x32_bf16(af, bfr, sacc[nt], 0, 0, 0);
        }
    }

    // ---- strided scores: 4 lanes per row, 16-d quarters ----
    const int sr = tid >> 2;          // 0..127
    const int dq = (tid & 3) * 16;
    if (nk > 0) {
        float qv[16];
#pragma unroll
        for (int d = 0; d < 16; d += 8) {
            union { uint4 v; ushort u[8]; } tmp;
            tmp.v = *(const uint4*)&Kw[128 + sr][dq + d];
#pragma unroll
            for (int j = 0; j < 8; ++j) qv[d + j] = bf2f(tmp.u[j]);
        }
        for (int k = 0; k < nk; ++k) {
            const ushort* kr = q_ws + qbase + (size_t)(k * 128 + sr) * 64 + dq;
            float p = 0.f;
#pragma unroll
            for (int d = 0; d < 16; d += 8) {
                union { uint4 v; ushort u[8]; } tmp;
                tmp.v = *(const uint4*)(kr + d);
#pragma unroll
                for (int jj = 0; jj < 8; ++jj) p += qv[d + jj] * bf2f(tmp.u[jj]);
            }
            p += __shfl_xor(p, 1);
            p += __shfl_xor(p, 2);
            if ((tid & 3) == 0)
                Sstr[sr][k] = p * 0.125f + am[k * 128 + sr];
        }
    }
    __syncthreads();

    // ---- softmax: wave owns rows r0..r0+15; all 16 lanes of a quad share rr,
    //      so lane l16 folds Sstr[rr][l16] into the shfl reduction (no nk loop)
#pragma unroll
    for (int reg = 0; reg < 4; ++reg) {
        int rr = r0 + quad * 4 + reg;
        float sv[16];
#pragma unroll
        for (int nt = 0; nt < 16; ++nt) {
            int c = nt * 16 + l16;
            bool allowed = (c >= rr) && (c <= rr + 128) && (t > 0 || c >= 128);
            int ci = base_row + c; if (ci < 0) ci = 0;
            sv[nt] = allowed ? sacc[nt][reg] * 0.125f + am[ci] : -INFINITY;
        }
        float sstr_v = (l16 < nk) ? Sstr[rr][l16] : -INFINITY;
        float m = sstr_v;
#pragma unroll
        for (int nt = 0; nt < 16; ++nt) m = fmaxf(m, sv[nt]);
#pragma unroll
        for (int off = 1; off < 16; off <<= 1) m = fmaxf(m, __shfl_xor(m, off));

        float es = (l16 < nk) ? __expf(sstr_v - m) : 0.f;
        float sum = es;
#pragma unroll
        for (int nt = 0; nt < 16; ++nt) {
            float e = (sv[nt] == -INFINITY) ? 0.f : __expf(sv[nt] - m);
            sv[nt] = e; sum += e;
        }
#pragma unroll
        for (int off = 1; off < 16; off <<= 1) sum += __shfl_xor(sum, off);
        float rden = 1.f / sum;
#pragma unroll
        for (int nt = 0; nt < 16; ++nt)
            Pl[rr][nt * 16 + l16] = f2bf(sv[nt] * rden);
        if (l16 < nk)
            Sstr[rr][l16] = es * rden;
    }
    __syncthreads();

    // ---- PV dense: rows [r0,r0+16) x 64 d, K=256 ----
    float4v cacc[4] = {};
#pragma unroll
    for (int ks = 0; ks < 8; ++ks) {
        short8 af = *(const short8*)&Pl[r0 + l16][ks * 32 + quad * 8];
#pragma unroll
        for (int nt = 0; nt < 4; ++nt) {
            short8 bfr = *(const short8*)&Vt[nt * 16 + l16][ks * 32 + quad * 8];
            cacc[nt] = __builtin_amdgcn_mfma_f32_16x16x32_bf16(af, bfr, cacc[nt], 0, 0, 0);
        }
    }
    __syncthreads();   // all Pl reads done; region reused as float ctx_part

    // ---- strided PV: 4 lanes/row, 16-d quarters, into ctx_part ----
    float* ctxp = (float*)&Pl[0][0];          // [128][68] fp32
    {
        float acc16[16] = {};
        for (int k = 0; k < nk; ++k) {
            float p = Sstr[sr][k];
            const ushort* vr = v_ws + qbase + (size_t)(k * 128 + sr) * 64 + dq;
#pragma unroll
            for (int d = 0; d < 16; d += 8) {
                union { uint4 v; ushort u[8]; } tmp;
                tmp.v = *(const uint4*)(vr + d);
#pragma unroll
                for (int j = 0; j < 8; ++j) acc16[d + j] += p * bf2f(tmp.u[j]);
            }
        }
#pragma unroll
        for (int d = 0; d < 16; d += 4)
            *(float4v*)&ctxp[sr * 68 + dq + d] = *(const float4v*)&acc16[d];
    }
    __syncthreads();

    // ---- epilogue: out[b][s][h*64+d], fp32 ----
    const size_t obase = ((size_t)b * 2048 + (size_t)t * 128) * 1024 + (size_t)h * 64;
#pragma unroll
    for (int nt = 0; nt < 4; ++nt)
#pragma unroll
        for (int reg = 0; reg < 4; ++reg) {
            int rr = r0 + quad * 4 + reg;
            int d = nt * 16 + l16;
            out[obase + (size_t)rr * 1024 + d] = cacc[nt][reg] + ctxp[rr * 68 + d];
        }
}

// ---------------------------------------------------------------------------
extern "C" void kernel_launch(void* const* d_in, const int* in_sizes, int n_in,
                              void* d_out, int out_size, void* d_ws, size_t ws_size,
                              hipStream_t stream) {
    int ihs = -1, iam = -1, iw1 = -1, iw2 = -1, ib1 = -1, ib2 = -1;
    for (int i = 0; i < n_in; ++i) {
        int s = in_sizes[i];
        if      (s == 4194304) { if (ihs < 0) ihs = i; }
        else if (s == 4096)    { if (iam < 0) iam = i; }
        else if (s == 1048576) { if (iw1 < 0) iw1 = i; else if (iw2 < 0) iw2 = i; }
        else if (s == 1024)    { if (ib1 < 0) ib1 = i; else if (ib2 < 0) ib2 = i; }
    }
    if (ihs < 0) ihs = 0; if (iam < 0) iam = 1;
    if (iw1 < 0) iw1 = 2; if (ib1 < 0) ib1 = 3;
    if (iw2 < 0) iw2 = 4; if (ib2 < 0) ib2 = 5;

    const float* hs    = (const float*)d_in[ihs];
    const float* amask = (const float*)d_in[iam];
    const float* Wq    = (const float*)d_in[iw1];
    const float* bq    = (const float*)d_in[ib1];
    const float* Wv    = (const float*)d_in[iw2];
    const float* bv    = (const float*)d_in[ib2];
    float* out = (float*)d_out;                    // fp32 output

    char* ws = (char*)d_ws;
    ushort* Wtq  = (ushort*)(ws);                          // 2 MB
    ushort* Wtv  = (ushort*)(ws + (1u << 21));             // 2 MB
    ushort* q_ws = (ushort*)(ws + (2u << 21));             // 8 MB
    ushort* v_ws = (ushort*)(ws + (2u << 21) + (1u << 23));// 8 MB

    transpose_w<<<dim3(16, 16, 2), 256, 0, stream>>>(Wq, Wv, Wtq, Wtv);
    qv_gemm<<<dim3(8, 32, 2), 256, 0, stream>>>(hs, Wtq, Wtv, bq, bv, q_ws, v_ws);
    attn<<<dim3(16, 16, 2), 512, 0, stream>>>(q_ws, v_ws, amask, out);
}

// Round 9
// 152.963 us; speedup vs baseline: 2.2139x; 1.0297x over previous
//
#include <hip/hip_runtime.h>

typedef __attribute__((ext_vector_type(8))) short short8;
typedef __attribute__((ext_vector_type(4))) float float4v;

__device__ inline float bf2f(ushort u) {
    unsigned v = ((unsigned)u) << 16;
    return __builtin_bit_cast(float, v);
}
__device__ inline ushort f2bf(float f) {
    unsigned u = __builtin_bit_cast(unsigned, f);
    u += 0x7FFFu + ((u >> 16) & 1u);   // RNE
    return (ushort)(u >> 16);
}

// ---------------------------------------------------------------------------
// Kernel 1: hs fp32 -> bf16 [4096][1024] (pure BW pass)
// ---------------------------------------------------------------------------
__global__ __launch_bounds__(256) void convert_hs(
    const float* __restrict__ hs, ushort* __restrict__ hsb) {
    const size_t base = ((size_t)blockIdx.x * 256 + threadIdx.x) * 16;
    union { ushort u[16]; uint4 v[2]; } o;
#pragma unroll
    for (int q = 0; q < 4; ++q) {
        float4v f = *(const float4v*)(hs + base + q * 4);
#pragma unroll
        for (int j = 0; j < 4; ++j) o.u[q * 4 + j] = f2bf(f[j]);
    }
    *(uint4*)(hsb + base)     = o.v[0];
    *(uint4*)(hsb + base + 8) = o.v[1];
}

// ---------------------------------------------------------------------------
// Kernel 2: W fp32 [K][N] -> Wt bf16 [N][K] (transpose + downcast)
// ---------------------------------------------------------------------------
__global__ __launch_bounds__(256) void transpose_w(
    const float* __restrict__ Wq, const float* __restrict__ Wv,
    ushort* __restrict__ Wtq, ushort* __restrict__ Wtv) {
    __shared__ ushort tile[64][68];
    const float* W = blockIdx.z ? Wv : Wq;
    ushort* Wt     = blockIdx.z ? Wtv : Wtq;
    const int k0 = blockIdx.y * 64, n0 = blockIdx.x * 64;
    const int tid = threadIdx.x;
    const int rr = tid >> 4;          // 0..15
    const int cc = (tid & 15) * 4;    // 0..60
    union U4 { ushort u[4]; uint2 v; };
#pragma unroll
    for (int i = 0; i < 4; ++i) {
        int row = rr + i * 16;
        float4v f = *(const float4v*)(W + (size_t)(k0 + row) * 1024 + n0 + cc);
        U4 x;
#pragma unroll
        for (int j = 0; j < 4; ++j) x.u[j] = f2bf(f[j]);
        *(uint2*)&tile[row][cc] = x.v;
    }
    __syncthreads();
#pragma unroll
    for (int i = 0; i < 4; ++i) {
        int row = rr + i * 16;        // n within tile
        U4 o;
#pragma unroll
        for (int j = 0; j < 4; ++j) o.u[j] = tile[cc + j][row];
        *(uint2*)(Wt + (size_t)(n0 + row) * 1024 + k0 + cc) = o.v;
    }
}

// ---------------------------------------------------------------------------
// Kernel 3: C = hsb @ Wt^T + b -> [B][H][S][64] bf16. 128x128 tile, BK=64,
// unpadded LDS [128][64] with XOR-chunk swizzle (phys = chunk ^ (row&7)):
// 16B-aligned b128 everywhere, <=2-way bank aliasing (free).
// ---------------------------------------------------------------------------
__global__ __launch_bounds__(256) void qv_gemm(
    const ushort* __restrict__ hsb,                                 // [4096][1024] bf16
    const ushort* __restrict__ Wtq, const ushort* __restrict__ Wtv, // [N][K] bf16
    const float* __restrict__ bq, const float* __restrict__ bv,     // fp32
    ushort* __restrict__ q_ws, ushort* __restrict__ v_ws) {
    __shared__ ushort Al[128 * 64];
    __shared__ ushort Bl[128 * 64];
    const ushort* Wt  = blockIdx.z ? Wtv : Wtq;
    const float* bias = blockIdx.z ? bv : bq;
    ushort* out       = blockIdx.z ? v_ws : q_ws;
    const int m0 = blockIdx.y * 128, n0 = blockIdx.x * 128;
    const int tid = threadIdx.x;
    const int wid = tid >> 6, lane = tid & 63;
    const int quad = lane >> 4, l16 = lane & 15;
    const int wm = (wid >> 1) * 64, wn = (wid & 1) * 64;

    float4v acc[4][4] = {};

    for (int kt = 0; kt < 1024; kt += 64) {
        __syncthreads();
#pragma unroll
        for (int i = 0; i < 4; ++i) {
            int u = tid + i * 256;           // 0..1023 : 128 rows x 8 chunks
            int row = u >> 3, c = u & 7;
            int p = c ^ (row & 7);
            *(uint4*)&Al[row * 64 + p * 8] =
                *(const uint4*)(hsb + (size_t)(m0 + row) * 1024 + kt + c * 8);
            *(uint4*)&Bl[row * 64 + p * 8] =
                *(const uint4*)(Wt + (size_t)(n0 + row) * 1024 + kt + c * 8);
        }
        __syncthreads();
#pragma unroll
        for (int ks = 0; ks < 2; ++ks) {
            short8 af[4], bfr[4];
#pragma unroll
            for (int mt = 0; mt < 4; ++mt) {
                int row = wm + mt * 16 + l16;
                af[mt] = *(const short8*)&Al[row * 64 + (((ks * 4 + quad) ^ (l16 & 7)) * 8)];
            }
#pragma unroll
            for (int nt = 0; nt < 4; ++nt) {
                int row = wn + nt * 16 + l16;
                bfr[nt] = *(const short8*)&Bl[row * 64 + (((ks * 4 + quad) ^ (l16 & 7)) * 8)];
            }
#pragma unroll
            for (int mt = 0; mt < 4; ++mt)
#pragma unroll
                for (int nt = 0; nt < 4; ++nt)
                    acc[mt][nt] = __builtin_amdgcn_mfma_f32_16x16x32_bf16(
                        af[mt], bfr[nt], acc[mt][nt], 0, 0, 0);
        }
    }
    // epilogue: C/D layout col=lane&15, row=quad*4+reg (HW-verified)
#pragma unroll
    for (int mt = 0; mt < 4; ++mt) {
#pragma unroll
        for (int nt = 0; nt < 4; ++nt) {
            int coln = n0 + wn + nt * 16 + l16;
            float bsv = bias[coln];
            int hh = coln >> 6, dd = coln & 63;
#pragma unroll
            for (int reg = 0; reg < 4; ++reg) {
                int r = m0 + wm + mt * 16 + quad * 4 + reg;   // 0..4095
                int bb = r >> 11, s = r & 2047;
                out[(((size_t)bb * 16 + hh) * 2048 + s) * 64 + dd] =
                    f2bf(acc[mt][nt][reg] + bsv);
            }
        }
    }
}

// ---------------------------------------------------------------------------
// Kernel 4: MFMA fused sparse attention, 64-row Q tiles, 192-col band,
// 256 threads (4 waves, 16 rows each). 61 KB LDS -> 2 blocks/CU.
// Pl aliases Kw (dead after strided scores); ctxp aliases Pl (dead after PV).
// ---------------------------------------------------------------------------
__global__ __launch_bounds__(256) void attn(
    const ushort* __restrict__ q_ws, const ushort* __restrict__ v_ws,
    const float* __restrict__ amask, float* __restrict__ out) {
    __shared__ __align__(16) char smem[62464];
    ushort (*Kw)[64]  = (ushort(*)[64])smem;              // 256x64: 0..191 keys, 192..255 Q
    ushort (*Pl)[192] = (ushort(*)[192])smem;             // 64x192 probs (aliases Kw)
    float*  ctxp      = (float*)smem;                     // 64x68 strided ctx (aliases Pl)
    ushort (*Vt)[192] = (ushort(*)[192])(smem + 32768);   // V^T [d][j]
    float  (*Sstr)[17] = (float(*)[17])(smem + 57344);    // strided scores/probs
    float*  amw       = (float*)(smem + 61696);           // window amask [192]

    const int t = blockIdx.x, h = blockIdx.y, b = blockIdx.z;
    const int tid = threadIdx.x;
    const int wid = tid >> 6, lane = tid & 63;
    const int quad = lane >> 4, l16 = lane & 15;
    const int r0 = wid * 16;
    const size_t qbase = ((size_t)b * 16 + h) * 2048 * 64;
    const int t0 = t * 64;                 // first q row
    const int bc = t0 - 128;               // first window col (may be <0)
    const int cmin = (t == 0) ? 128 : (t == 1 ? 64 : 0);
    const int nk = (t >= 4) ? ((t >> 1) - 1) : 0;   // strided singles per row

    // ---- stage ----
    if (tid < 192) {
        int j = bc + tid; if (j < 0) j = 0;
        amw[tid] = amask[(size_t)b * 2048 + j];
    }
#pragma unroll
    for (int i = 0; i < 8; ++i) {
        int u = tid + i * 256;             // 256 rows x 8 chunks
        int row = u >> 3, c = u & 7;
        int jg = (row < 192) ? (bc + row) : (t0 + row - 192);
        if (jg < 0) jg = 0;                // masked anyway
        int p = c ^ (row & 7);
        *(uint4*)&Kw[row][p * 8] = *(const uint4*)(q_ws + qbase + (size_t)jg * 64 + c * 8);
    }
    // Vt via register transpose: 384 units: j0=(u%48)*4, d0=(u/48)*8
#pragma unroll
    for (int i = 0; i < 2; ++i) {
        int u = tid + i * 256;
        if (u < 384) {
            int j0 = (u % 48) * 4, d0 = (u / 48) * 8;
            ushort vreg[4][8];
#pragma unroll
            for (int jj = 0; jj < 4; ++jj) {
                int jg = bc + j0 + jj; if (jg < 0) jg = 0;
                *(uint4*)vreg[jj] = *(const uint4*)(v_ws + qbase + (size_t)jg * 64 + d0);
            }
#pragma unroll
            for (int dd = 0; dd < 8; ++dd) {
                int row = d0 + dd;
                int p = (j0 >> 3) ^ (row & 7);
                union { ushort u4[4]; uint2 v; } pk;
                pk.u4[0] = vreg[0][dd]; pk.u4[1] = vreg[1][dd];
                pk.u4[2] = vreg[2][dd]; pk.u4[3] = vreg[3][dd];
                *(uint2*)&Vt[row][p * 8 + (j0 & 7)] = pk.v;
            }
        }
    }
    __syncthreads();

    // ---- QK^T dense band: wave -> rows [r0,r0+16) x 192 cols ----
    float4v sacc[12] = {};
#pragma unroll
    for (int ks = 0; ks < 2; ++ks) {
        int sw = ((ks * 4 + quad) ^ (l16 & 7)) * 8;
        short8 af = *(const short8*)&Kw[192 + r0 + l16][sw];
#pragma unroll
        for (int nt = 0; nt < 12; ++nt) {
            short8 bfr = *(const short8*)&Kw[nt * 16 + l16][sw];
            sacc[nt] = __builtin_amdgcn_mfma_f32_16x16x32_bf16(af, bfr, sacc[nt], 0, 0, 0);
        }
    }

    // ---- strided scores: 4 lanes/row, 16-d quarters ----
    const int sr = tid >> 2;               // 0..63
    const int dq = (tid & 3) * 16;
    const int smod = (t0 + sr) & 127;
    if (nk > 0) {
        float qv[16];
#pragma unroll
        for (int cc = 0; cc < 2; ++cc) {
            int c = (dq >> 3) + cc;
            int p = c ^ (sr & 7);          // (192+sr)&7 == sr&7
            union { uint4 v; ushort u[8]; } tm;
            tm.v = *(const uint4*)&Kw[192 + sr][p * 8];
#pragma unroll
            for (int jj = 0; jj < 8; ++jj) qv[cc * 8 + jj] = bf2f(tm.u[jj]);
        }
        for (int m = 0; m < nk; ++m) {
            const ushort* kr = q_ws + qbase + (size_t)(smod + (m << 7)) * 64 + dq;
            float p = 0.f;
#pragma unroll
            for (int d = 0; d < 16; d += 8) {
                union { uint4 v; ushort u[8]; } tm;
                tm.v = *(const uint4*)(kr + d);
#pragma unroll
                for (int jj = 0; jj < 8; ++jj) p += qv[d + jj] * bf2f(tm.u[jj]);
            }
            p += __shfl_xor(p, 1);
            p += __shfl_xor(p, 2);
            if ((tid & 3) == 0)
                Sstr[sr][m] = p * 0.125f + amask[(size_t)b * 2048 + smod + (m << 7)];
        }
    }
    __syncthreads();   // Kw dead from here; region becomes Pl

    // ---- softmax per row; quad's 16 lanes fold Sstr via the shfl reduction ----
#pragma unroll
    for (int reg = 0; reg < 4; ++reg) {
        int rr = r0 + quad * 4 + reg;
        float sv[12];
#pragma unroll
        for (int nt = 0; nt < 12; ++nt) {
            int c = nt * 16 + l16;
            bool allowed = (c >= rr) && (c <= rr + 128) && (c >= cmin);
            sv[nt] = allowed ? sacc[nt][reg] * 0.125f + amw[c] : -INFINITY;
        }
        float sstr_v = (l16 < nk) ? Sstr[rr][l16] : -INFINITY;
        float m = sstr_v;
#pragma unroll
        for (int nt = 0; nt < 12; ++nt) m = fmaxf(m, sv[nt]);
#pragma unroll
        for (int off = 1; off < 16; off <<= 1) m = fmaxf(m, __shfl_xor(m, off));

        float es = (l16 < nk) ? __expf(sstr_v - m) : 0.f;
        float sum = es;
#pragma unroll
        for (int nt = 0; nt < 12; ++nt) {
            float e = (sv[nt] == -INFINITY) ? 0.f : __expf(sv[nt] - m);
            sv[nt] = e; sum += e;
        }
#pragma unroll
        for (int off = 1; off < 16; off <<= 1) sum += __shfl_xor(sum, off);
        float rden = 1.f / sum;
#pragma unroll
        for (int nt = 0; nt < 12; ++nt) {
            int c = nt * 16 + l16;
            int p = ((c >> 3) ^ (rr & 7));
            Pl[rr][p * 8 + (c & 7)] = f2bf(sv[nt] * rden);
        }
        if (l16 < nk) Sstr[rr][l16] = es * rden;
    }
    __syncthreads();

    // ---- PV dense: rows [r0,r0+16) x 64 d, K=192 ----
    float4v cacc[4] = {};
#pragma unroll
    for (int ks = 0; ks < 6; ++ks) {
        int chunk = ks * 4 + quad;
        int sw = (chunk ^ (l16 & 7)) * 8;
        short8 af = *(const short8*)&Pl[r0 + l16][sw];
#pragma unroll
        for (int nt = 0; nt < 4; ++nt) {
            short8 bfr = *(const short8*)&Vt[nt * 16 + l16][sw];
            cacc[nt] = __builtin_amdgcn_mfma_f32_16x16x32_bf16(af, bfr, cacc[nt], 0, 0, 0);
        }
    }
    __syncthreads();   // Pl dead; region becomes ctxp

    // ---- strided PV: 4 lanes/row, 16-d quarters, into ctxp ----
    {
        float acc16[16] = {};
        for (int m = 0; m < nk; ++m) {
            float p = Sstr[sr][m];
            const ushort* vr = v_ws + qbase + (size_t)(smod + (m << 7)) * 64 + dq;
#pragma unroll
            for (int d = 0; d < 16; d += 8) {
                union { uint4 v; ushort u[8]; } tm;
                tm.v = *(const uint4*)(vr + d);
#pragma unroll
                for (int jj = 0; jj < 8; ++jj) acc16[d + jj] += p * bf2f(tm.u[jj]);
            }
        }
#pragma unroll
        for (int d = 0; d < 16; d += 4)
            *(float4v*)&ctxp[sr * 68 + dq + d] = *(const float4v*)&acc16[d];
    }
    __syncthreads();

    // ---- epilogue: out[b][s][h*64+d], fp32 ----
    const size_t obase = ((size_t)b * 2048 + t0) * 1024 + (size_t)h * 64;
#pragma unroll
    for (int nt = 0; nt < 4; ++nt)
#pragma unroll
        for (int reg = 0; reg < 4; ++reg) {
            int rr = r0 + quad * 4 + reg;
            int d = nt * 16 + l16;
            out[obase + (size_t)rr * 1024 + d] = cacc[nt][reg] + ctxp[rr * 68 + d];
        }
}

// ---------------------------------------------------------------------------
extern "C" void kernel_launch(void* const* d_in, const int* in_sizes, int n_in,
                              void* d_out, int out_size, void* d_ws, size_t ws_size,
                              hipStream_t stream) {
    int ihs = -1, iam = -1, iw1 = -1, iw2 = -1, ib1 = -1, ib2 = -1;
    for (int i = 0; i < n_in; ++i) {
        int s = in_sizes[i];
        if      (s == 4194304) { if (ihs < 0) ihs = i; }
        else if (s == 4096)    { if (iam < 0) iam = i; }
        else if (s == 1048576) { if (iw1 < 0) iw1 = i; else if (iw2 < 0) iw2 = i; }
        else if (s == 1024)    { if (ib1 < 0) ib1 = i; else if (ib2 < 0) ib2 = i; }
    }
    if (ihs < 0) ihs = 0; if (iam < 0) iam = 1;
    if (iw1 < 0) iw1 = 2; if (ib1 < 0) ib1 = 3;
    if (iw2 < 0) iw2 = 4; if (ib2 < 0) ib2 = 5;

    const float* hs    = (const float*)d_in[ihs];
    const float* amask = (const float*)d_in[iam];
    const float* Wq    = (const float*)d_in[iw1];
    const float* bq    = (const float*)d_in[ib1];
    const float* Wv    = (const float*)d_in[iw2];
    const float* bv    = (const float*)d_in[ib2];
    float* out = (float*)d_out;                    // fp32 output

    char* ws = (char*)d_ws;
    ushort* Wtq  = (ushort*)(ws);                           // 2 MB
    ushort* Wtv  = (ushort*)(ws + (1u << 21));              // 2 MB
    ushort* hsb  = (ushort*)(ws + (2u << 21));              // 8 MB
    ushort* q_ws = (ushort*)(ws + (2u << 21) + (1u << 23)); // 8 MB
    ushort* v_ws = (ushort*)(ws + (2u << 21) + (2u << 23)); // 8 MB

    convert_hs<<<1024, 256, 0, stream>>>(hs, hsb);
    transpose_w<<<dim3(16, 16, 2), 256, 0, stream>>>(Wq, Wv, Wtq, Wtv);
    qv_gemm<<<dim3(8, 32, 2), 256, 0, stream>>>(hsb, Wtq, Wtv, bq, bv, q_ws, v_ws);
    attn<<<dim3(32, 16, 2), 256, 0, stream>>>(q_ws, v_ws, amask, out);
}

// Round 10
// 152.125 us; speedup vs baseline: 2.2261x; 1.0055x over previous
//
#include <hip/hip_runtime.h>

typedef __attribute__((ext_vector_type(8))) short short8;
typedef __attribute__((ext_vector_type(4))) float float4v;

__device__ inline float bf2f(ushort u) {
    unsigned v = ((unsigned)u) << 16;
    return __builtin_bit_cast(float, v);
}
__device__ inline ushort f2bf(float f) {
    unsigned u = __builtin_bit_cast(unsigned, f);
    u += 0x7FFFu + ((u >> 16) & 1u);   // RNE
    return (ushort)(u >> 16);
}

// async global->LDS, 16B per lane; LDS dest = wave-uniform base + lane*16
__device__ inline void gload_lds16(const ushort* g, ushort* l) {
    __builtin_amdgcn_global_load_lds(
        (const __attribute__((address_space(1))) unsigned int*)g,
        (__attribute__((address_space(3))) unsigned int*)l,
        16, 0, 0);
}

// ---------------------------------------------------------------------------
// Kernel 1: hs fp32 -> bf16 [4096][1024] (pure BW pass)
// ---------------------------------------------------------------------------
__global__ __launch_bounds__(256) void convert_hs(
    const float* __restrict__ hs, ushort* __restrict__ hsb) {
    const size_t base = ((size_t)blockIdx.x * 256 + threadIdx.x) * 16;
    union { ushort u[16]; uint4 v[2]; } o;
#pragma unroll
    for (int q = 0; q < 4; ++q) {
        float4v f = *(const float4v*)(hs + base + q * 4);
#pragma unroll
        for (int j = 0; j < 4; ++j) o.u[q * 4 + j] = f2bf(f[j]);
    }
    *(uint4*)(hsb + base)     = o.v[0];
    *(uint4*)(hsb + base + 8) = o.v[1];
}

// ---------------------------------------------------------------------------
// Kernel 2: W fp32 [K][N] -> Wt bf16 [N][K] (transpose + downcast)
// ---------------------------------------------------------------------------
__global__ __launch_bounds__(256) void transpose_w(
    const float* __restrict__ Wq, const float* __restrict__ Wv,
    ushort* __restrict__ Wtq, ushort* __restrict__ Wtv) {
    __shared__ ushort tile[64][68];
    const float* W = blockIdx.z ? Wv : Wq;
    ushort* Wt     = blockIdx.z ? Wtv : Wtq;
    const int k0 = blockIdx.y * 64, n0 = blockIdx.x * 64;
    const int tid = threadIdx.x;
    const int rr = tid >> 4;          // 0..15
    const int cc = (tid & 15) * 4;    // 0..60
    union U4 { ushort u[4]; uint2 v; };
#pragma unroll
    for (int i = 0; i < 4; ++i) {
        int row = rr + i * 16;
        float4v f = *(const float4v*)(W + (size_t)(k0 + row) * 1024 + n0 + cc);
        U4 x;
#pragma unroll
        for (int j = 0; j < 4; ++j) x.u[j] = f2bf(f[j]);
        *(uint2*)&tile[row][cc] = x.v;
    }
    __syncthreads();
#pragma unroll
    for (int i = 0; i < 4; ++i) {
        int row = rr + i * 16;        // n within tile
        U4 o;
#pragma unroll
        for (int j = 0; j < 4; ++j) o.u[j] = tile[cc + j][row];
        *(uint2*)(Wt + (size_t)(n0 + row) * 1024 + k0 + cc) = o.v;
    }
}

// ---------------------------------------------------------------------------
// Kernel 3: C = hsb @ Wt^T + b -> [B][H][S][64] bf16. m97-style:
// global_load_lds width=16 staging into contiguous [128][64] LDS tiles,
// 2-barrier K-loop, 128x128 tile, BK=64.
// ---------------------------------------------------------------------------
__global__ __launch_bounds__(256) void qv_gemm(
    const ushort* __restrict__ hsb,                                 // [4096][1024] bf16
    const ushort* __restrict__ Wtq, const ushort* __restrict__ Wtv, // [N][K] bf16
    const float* __restrict__ bq, const float* __restrict__ bv,     // fp32
    ushort* __restrict__ q_ws, ushort* __restrict__ v_ws) {
    __shared__ ushort Al[128 * 64];
    __shared__ ushort Bl[128 * 64];
    const ushort* Wt  = blockIdx.z ? Wtv : Wtq;
    const float* bias = blockIdx.z ? bv : bq;
    ushort* out       = blockIdx.z ? v_ws : q_ws;
    const int m0 = blockIdx.y * 128, n0 = blockIdx.x * 128;
    const int tid = threadIdx.x;
    const int wid = tid >> 6, lane = tid & 63;
    const int quad = lane >> 4, l16 = lane & 15;
    const int wm = (wid >> 1) * 64, wn = (wid & 1) * 64;
    const int rbase = 32 * wid;               // staging rows for this wave
    const int srow = lane >> 3, scol = (lane & 7) * 8;

    float4v acc[4][4] = {};

    for (int kt = 0; kt < 1024; kt += 64) {
        __syncthreads();
        // async stage: wave fills rows rbase..rbase+31 of Al and Bl
#pragma unroll
        for (int c8 = 0; c8 < 4; ++c8) {
            int row = rbase + c8 * 8;
            gload_lds16(hsb + (size_t)(m0 + row + srow) * 1024 + kt + scol,
                        &Al[row * 64]);
            gload_lds16(Wt + (size_t)(n0 + row + srow) * 1024 + kt + scol,
                        &Bl[row * 64]);
        }
        __syncthreads();   // implies vmcnt(0): async loads drained
#pragma unroll
        for (int ks = 0; ks < 2; ++ks) {
            short8 af[4], bfr[4];
#pragma unroll
            for (int mt = 0; mt < 4; ++mt)
                af[mt] = *(const short8*)&Al[(wm + mt * 16 + l16) * 64 + (ks * 4 + quad) * 8];
#pragma unroll
            for (int nt = 0; nt < 4; ++nt)
                bfr[nt] = *(const short8*)&Bl[(wn + nt * 16 + l16) * 64 + (ks * 4 + quad) * 8];
#pragma unroll
            for (int mt = 0; mt < 4; ++mt)
#pragma unroll
                for (int nt = 0; nt < 4; ++nt)
                    acc[mt][nt] = __builtin_amdgcn_mfma_f32_16x16x32_bf16(
                        af[mt], bfr[nt], acc[mt][nt], 0, 0, 0);
        }
    }
    // epilogue: C/D layout col=lane&15, row=quad*4+reg (HW-verified)
#pragma unroll
    for (int mt = 0; mt < 4; ++mt) {
#pragma unroll
        for (int nt = 0; nt < 4; ++nt) {
            int coln = n0 + wn + nt * 16 + l16;
            float bsv = bias[coln];
            int hh = coln >> 6, dd = coln & 63;
#pragma unroll
            for (int reg = 0; reg < 4; ++reg) {
                int r = m0 + wm + mt * 16 + quad * 4 + reg;   // 0..4095
                int bb = r >> 11, s = r & 2047;
                out[(((size_t)bb * 16 + hh) * 2048 + s) * 64 + dd] =
                    f2bf(acc[mt][nt][reg] + bsv);
            }
        }
    }
}

// ---------------------------------------------------------------------------
// Kernel 4: MFMA fused sparse attention (R8-proven), 512 threads, 128-row
// Q tiles x 256-col band, + XCD-aware (t,h) remap for L2 window reuse.
// ---------------------------------------------------------------------------
__global__ __launch_bounds__(512) void attn(
    const ushort* __restrict__ q_ws, const ushort* __restrict__ v_ws,
    const float* __restrict__ amask, float* __restrict__ out) {
    // XCD-aware remap: same-XCD blocks get consecutive t of the same head
    const int lin = blockIdx.x + 16 * blockIdx.y;   // 0..255
    const int u8 = lin & 7, v32 = lin >> 3;
    const int t = v32 & 15;
    const int h = u8 + ((v32 >> 4) << 3);
    const int b = blockIdx.z;

    __shared__ ushort Kw[256][72];    // window rows; upper 128 = Q tile t
    __shared__ ushort Vt[64][266];    // V window transposed [d][j]
    __shared__ ushort Pl[128][266];   // probs bf16; later float ctx_part[128][68]
    __shared__ float  Sstr[128][17];  // strided scores -> probs
    __shared__ float  am[2048];       // attention_mask row for this b

    const int tid = threadIdx.x;      // 0..511
    const int wid = tid >> 6, lane = tid & 63;
    const int quad = lane >> 4, l16 = lane & 15;
    const int r0 = wid * 16;          // wave's 16-row M-tile base
    const size_t qbase = ((size_t)b * 16 + h) * 2048 * 64;
    const int base_row = (t - 1) * 128;
    const int nk = (t >= 2) ? (t - 1) : 0;   // strided keys per row

    // ---- stage ----
    *(float4v*)&am[tid * 4] = *(const float4v*)(amask + (size_t)b * 2048 + tid * 4);
#pragma unroll
    for (int i = 0; i < 4; ++i) {
        int c = tid + i * 512;
        int row = c >> 3, col = (c & 7) * 8;
        int jg = base_row + row; if (jg < 0) jg = 0;   // t=0 lower half masked anyway
        *(uint4*)&Kw[row][col] = *(const uint4*)(q_ws + qbase + (size_t)jg * 64 + col);
    }
    {   // Vt: wave-contiguous j, one 32-d half per thread-half
        int j = tid & 255, dh0 = (tid >> 8) * 32;
        int jg = base_row + j; if (jg < 0) jg = 0;
        const ushort* src = v_ws + qbase + (size_t)jg * 64 + dh0;
#pragma unroll
        for (int d = 0; d < 32; d += 8) {
            union { uint4 v; ushort u[8]; } tmp;
            tmp.v = *(const uint4*)(src + d);
#pragma unroll
            for (int jj = 0; jj < 8; ++jj) Vt[dh0 + d + jj][j] = tmp.u[jj];
        }
    }
    __syncthreads();

    // ---- QK^T dense band: wave w -> rows [r0,r0+16) x 256 cols ----
    float4v sacc[16] = {};
#pragma unroll
    for (int ks = 0; ks < 2; ++ks) {
        short8 af = *(const short8*)&Kw[128 + r0 + l16][ks * 32 + quad * 8];
#pragma unroll
        for (int nt = 0; nt < 16; ++nt) {
            short8 bfr = *(const short8*)&Kw[nt * 16 + l16][ks * 32 + quad * 8];
            sacc[nt] = __builtin_amdgcn_mfma_f32_16x16x32_bf16(af, bfr, sacc[nt], 0, 0, 0);
        }
    }

    // ---- strided scores: 4 lanes per row, 16-d quarters ----
    const int sr = tid >> 2;          // 0..127
    const int dq = (tid & 3) * 16;
    if (nk > 0) {
        float qv[16];
#pragma unroll
        for (int d = 0; d < 16; d += 8) {
            union { uint4 v; ushort u[8]; } tmp;
            tmp.v = *(const uint4*)&Kw[128 + sr][dq + d];
#pragma unroll
            for (int j = 0; j < 8; ++j) qv[d + j] = bf2f(tmp.u[j]);
        }
        for (int k = 0; k < nk; ++k) {
            const ushort* kr = q_ws + qbase + (size_t)(k * 128 + sr) * 64 + dq;
            float p = 0.f;
#pragma unroll
            for (int d = 0; d < 16; d += 8) {
                union { uint4 v; ushort u[8]; } tmp;
                tmp.v = *(const uint4*)(kr + d);
#pragma unroll
                for (int jj = 0; jj < 8; ++jj) p += qv[d + jj] * bf2f(tmp.u[jj]);
            }
            p += __shfl_xor(p, 1);
            p += __shfl_xor(p, 2);
            if ((tid & 3) == 0)
                Sstr[sr][k] = p * 0.125f + am[k * 128 + sr];
        }
    }
    __syncthreads();

    // ---- softmax: wave owns rows r0..r0+15; quad's 16 lanes fold Sstr ----
#pragma unroll
    for (int reg = 0; reg < 4; ++reg) {
        int rr = r0 + quad * 4 + reg;
        float sv[16];
#pragma unroll
        for (int nt = 0; nt < 16; ++nt) {
            int c = nt * 16 + l16;
            bool allowed = (c >= rr) && (c <= rr + 128) && (t > 0 || c >= 128);
            int ci = base_row + c; if (ci < 0) ci = 0;
            sv[nt] = allowed ? sacc[nt][reg] * 0.125f + am[ci] : -INFINITY;
        }
        float sstr_v = (l16 < nk) ? Sstr[rr][l16] : -INFINITY;
        float m = sstr_v;
#pragma unroll
        for (int nt = 0; nt < 16; ++nt) m = fmaxf(m, sv[nt]);
#pragma unroll
        for (int off = 1; off < 16; off <<= 1) m = fmaxf(m, __shfl_xor(m, off));

        float es = (l16 < nk) ? __expf(sstr_v - m) : 0.f;
        float sum = es;
#pragma unroll
        for (int nt = 0; nt < 16; ++nt) {
            float e = (sv[nt] == -INFINITY) ? 0.f : __expf(sv[nt] - m);
            sv[nt] = e; sum += e;
        }
#pragma unroll
        for (int off = 1; off < 16; off <<= 1) sum += __shfl_xor(sum, off);
        float rden = 1.f / sum;
#pragma unroll
        for (int nt = 0; nt < 16; ++nt)
            Pl[rr][nt * 16 + l16] = f2bf(sv[nt] * rden);
        if (l16 < nk)
            Sstr[rr][l16] = es * rden;
    }
    __syncthreads();

    // ---- PV dense: rows [r0,r0+16) x 64 d, K=256 ----
    float4v cacc[4] = {};
#pragma unroll
    for (int ks = 0; ks < 8; ++ks) {
        short8 af = *(const short8*)&Pl[r0 + l16][ks * 32 + quad * 8];
#pragma unroll
        for (int nt = 0; nt < 4; ++nt) {
            short8 bfr = *(const short8*)&Vt[nt * 16 + l16][ks * 32 + quad * 8];
            cacc[nt] = __builtin_amdgcn_mfma_f32_16x16x32_bf16(af, bfr, cacc[nt], 0, 0, 0);
        }
    }
    __syncthreads();   // all Pl reads done; region reused as float ctx_part

    // ---- strided PV: 4 lanes/row, 16-d quarters, into ctx_part ----
    float* ctxp = (float*)&Pl[0][0];          // [128][68] fp32
    {
        float acc16[16] = {};
        for (int k = 0; k < nk; ++k) {
            float p = Sstr[sr][k];
            const ushort* vr = v_ws + qbase + (size_t)(k * 128 + sr) * 64 + dq;
#pragma unroll
            for (int d = 0; d < 16; d += 8) {
                union { uint4 v; ushort u[8]; } tmp;
                tmp.v = *(const uint4*)(vr + d);
#pragma unroll
                for (int j = 0; j < 8; ++j) acc16[d + j] += p * bf2f(tmp.u[j]);
            }
        }
#pragma unroll
        for (int d = 0; d < 16; d += 4)
            *(float4v*)&ctxp[sr * 68 + dq + d] = *(const float4v*)&acc16[d];
    }
    __syncthreads();

    // ---- epilogue: out[b][s][h*64+d], fp32 ----
    const size_t obase = ((size_t)b * 2048 + (size_t)t * 128) * 1024 + (size_t)h * 64;
#pragma unroll
    for (int nt = 0; nt < 4; ++nt)
#pragma unroll
        for (int reg = 0; reg < 4; ++reg) {
            int rr = r0 + quad * 4 + reg;
            int d = nt * 16 + l16;
            out[obase + (size_t)rr * 1024 + d] = cacc[nt][reg] + ctxp[rr * 68 + d];
        }
}

// ---------------------------------------------------------------------------
extern "C" void kernel_launch(void* const* d_in, const int* in_sizes, int n_in,
                              void* d_out, int out_size, void* d_ws, size_t ws_size,
                              hipStream_t stream) {
    int ihs = -1, iam = -1, iw1 = -1, iw2 = -1, ib1 = -1, ib2 = -1;
    for (int i = 0; i < n_in; ++i) {
        int s = in_sizes[i];
        if      (s == 4194304) { if (ihs < 0) ihs = i; }
        else if (s == 4096)    { if (iam < 0) iam = i; }
        else if (s == 1048576) { if (iw1 < 0) iw1 = i; else if (iw2 < 0) iw2 = i; }
        else if (s == 1024)    { if (ib1 < 0) ib1 = i; else if (ib2 < 0) ib2 = i; }
    }
    if (ihs < 0) ihs = 0; if (iam < 0) iam = 1;
    if (iw1 < 0) iw1 = 2; if (ib1 < 0) ib1 = 3;
    if (iw2 < 0) iw2 = 4; if (ib2 < 0) ib2 = 5;

    const float* hs    = (const float*)d_in[ihs];
    const float* amask = (const float*)d_in[iam];
    const float* Wq    = (const float*)d_in[iw1];
    const float* bq    = (const float*)d_in[ib1];
    const float* Wv    = (const float*)d_in[iw2];
    const float* bv    = (const float*)d_in[ib2];
    float* out = (float*)d_out;                    // fp32 output

    char* ws = (char*)d_ws;
    ushort* Wtq  = (ushort*)(ws);                           // 2 MB
    ushort* Wtv  = (ushort*)(ws + (1u << 21));              // 2 MB
    ushort* hsb  = (ushort*)(ws + (2u << 21));              // 8 MB
    ushort* q_ws = (ushort*)(ws + (2u << 21) + (1u << 23)); // 8 MB
    ushort* v_ws = (ushort*)(ws + (2u << 21) + (2u << 23)); // 8 MB

    convert_hs<<<1024, 256, 0, stream>>>(hs, hsb);
    transpose_w<<<dim3(16, 16, 2), 256, 0, stream>>>(Wq, Wv, Wtq, Wtv);
    qv_gemm<<<dim3(8, 32, 2), 256, 0, stream>>>(hsb, Wtq, Wtv, bq, bv, q_ws, v_ws);
    attn<<<dim3(16, 16, 2), 512, 0, stream>>>(q_ws, v_ws, amask, out);
}

// Round 11
// 149.739 us; speedup vs baseline: 2.2615x; 1.0159x over previous
//
#include <hip/hip_runtime.h>

typedef __attribute__((ext_vector_type(8))) short short8;
typedef __attribute__((ext_vector_type(4))) float float4v;

__device__ inline float bf2f(ushort u) {
    unsigned v = ((unsigned)u) << 16;
    return __builtin_bit_cast(float, v);
}
__device__ inline ushort f2bf(float f) {
    unsigned u = __builtin_bit_cast(unsigned, f);
    u += 0x7FFFu + ((u >> 16) & 1u);   // RNE
    return (ushort)(u >> 16);
}

// async global->LDS, 16B per lane; LDS dest = wave-uniform base + lane*16
__device__ inline void gload_lds16(const ushort* g, ushort* l) {
    __builtin_amdgcn_global_load_lds(
        (const __attribute__((address_space(1))) unsigned int*)g,
        (__attribute__((address_space(3))) unsigned int*)l,
        16, 0, 0);
}

// ---------------------------------------------------------------------------
// Kernel 1: hs fp32 -> bf16 [4096][1024] (pure BW pass)
// ---------------------------------------------------------------------------
__global__ __launch_bounds__(256) void convert_hs(
    const float* __restrict__ hs, ushort* __restrict__ hsb) {
    const size_t base = ((size_t)blockIdx.x * 256 + threadIdx.x) * 16;
    union { ushort u[16]; uint4 v[2]; } o;
#pragma unroll
    for (int q = 0; q < 4; ++q) {
        float4v f = *(const float4v*)(hs + base + q * 4);
#pragma unroll
        for (int j = 0; j < 4; ++j) o.u[q * 4 + j] = f2bf(f[j]);
    }
    *(uint4*)(hsb + base)     = o.v[0];
    *(uint4*)(hsb + base + 8) = o.v[1];
}

// ---------------------------------------------------------------------------
// Kernel 2: W fp32 [K][N] -> Wt bf16 [N][K] (transpose + downcast)
// ---------------------------------------------------------------------------
__global__ __launch_bounds__(256) void transpose_w(
    const float* __restrict__ Wq, const float* __restrict__ Wv,
    ushort* __restrict__ Wtq, ushort* __restrict__ Wtv) {
    __shared__ ushort tile[64][68];
    const float* W = blockIdx.z ? Wv : Wq;
    ushort* Wt     = blockIdx.z ? Wtv : Wtq;
    const int k0 = blockIdx.y * 64, n0 = blockIdx.x * 64;
    const int tid = threadIdx.x;
    const int rr = tid >> 4;          // 0..15
    const int cc = (tid & 15) * 4;    // 0..60
    union U4 { ushort u[4]; uint2 v; };
#pragma unroll
    for (int i = 0; i < 4; ++i) {
        int row = rr + i * 16;
        float4v f = *(const float4v*)(W + (size_t)(k0 + row) * 1024 + n0 + cc);
        U4 x;
#pragma unroll
        for (int j = 0; j < 4; ++j) x.u[j] = f2bf(f[j]);
        *(uint2*)&tile[row][cc] = x.v;
    }
    __syncthreads();
#pragma unroll
    for (int i = 0; i < 4; ++i) {
        int row = rr + i * 16;        // n within tile
        U4 o;
#pragma unroll
        for (int j = 0; j < 4; ++j) o.u[j] = tile[cc + j][row];
        *(uint2*)(Wt + (size_t)(n0 + row) * 1024 + k0 + cc) = o.v;
    }
}

// ---------------------------------------------------------------------------
// Kernel 3: C = hsb @ Wt^T + b -> [B][H][S][64] bf16. m97-style (unchanged
// from R10): global_load_lds width=16, 2-barrier K-loop, 128x128, BK=64.
// ---------------------------------------------------------------------------
__global__ __launch_bounds__(256) void qv_gemm(
    const ushort* __restrict__ hsb,
    const ushort* __restrict__ Wtq, const ushort* __restrict__ Wtv,
    const float* __restrict__ bq, const float* __restrict__ bv,
    ushort* __restrict__ q_ws, ushort* __restrict__ v_ws) {
    __shared__ ushort Al[128 * 64];
    __shared__ ushort Bl[128 * 64];
    const ushort* Wt  = blockIdx.z ? Wtv : Wtq;
    const float* bias = blockIdx.z ? bv : bq;
    ushort* out       = blockIdx.z ? v_ws : q_ws;
    const int m0 = blockIdx.y * 128, n0 = blockIdx.x * 128;
    const int tid = threadIdx.x;
    const int wid = tid >> 6, lane = tid & 63;
    const int quad = lane >> 4, l16 = lane & 15;
    const int wm = (wid >> 1) * 64, wn = (wid & 1) * 64;
    const int rbase = 32 * wid;
    const int srow = lane >> 3, scol = (lane & 7) * 8;

    float4v acc[4][4] = {};

    for (int kt = 0; kt < 1024; kt += 64) {
        __syncthreads();
#pragma unroll
        for (int c8 = 0; c8 < 4; ++c8) {
            int row = rbase + c8 * 8;
            gload_lds16(hsb + (size_t)(m0 + row + srow) * 1024 + kt + scol,
                        &Al[row * 64]);
            gload_lds16(Wt + (size_t)(n0 + row + srow) * 1024 + kt + scol,
                        &Bl[row * 64]);
        }
        __syncthreads();
#pragma unroll
        for (int ks = 0; ks < 2; ++ks) {
            short8 af[4], bfr[4];
#pragma unroll
            for (int mt = 0; mt < 4; ++mt)
                af[mt] = *(const short8*)&Al[(wm + mt * 16 + l16) * 64 + (ks * 4 + quad) * 8];
#pragma unroll
            for (int nt = 0; nt < 4; ++nt)
                bfr[nt] = *(const short8*)&Bl[(wn + nt * 16 + l16) * 64 + (ks * 4 + quad) * 8];
#pragma unroll
            for (int mt = 0; mt < 4; ++mt)
#pragma unroll
                for (int nt = 0; nt < 4; ++nt)
                    acc[mt][nt] = __builtin_amdgcn_mfma_f32_16x16x32_bf16(
                        af[mt], bfr[nt], acc[mt][nt], 0, 0, 0);
        }
    }
#pragma unroll
    for (int mt = 0; mt < 4; ++mt) {
#pragma unroll
        for (int nt = 0; nt < 4; ++nt) {
            int coln = n0 + wn + nt * 16 + l16;
            float bsv = bias[coln];
            int hh = coln >> 6, dd = coln & 63;
#pragma unroll
            for (int reg = 0; reg < 4; ++reg) {
                int r = m0 + wm + mt * 16 + quad * 4 + reg;
                int bb = r >> 11, s = r & 2047;
                out[(((size_t)bb * 16 + hh) * 2048 + s) * 64 + dd] =
                    f2bf(acc[mt][nt][reg] + bsv);
            }
        }
    }
}

// ---------------------------------------------------------------------------
// Kernel 4: MFMA fused sparse attention v3. 512 threads, 128-row x 256-col
// tile, 73.5 KB LDS -> 2 blocks/CU. Two-pass PV with P-half aliasing Kw;
// ctxp aliases Vt. XOR-chunk swizzles (16B-aligned, <=2-way).
// ---------------------------------------------------------------------------
__global__ __launch_bounds__(512, 4) void attn(
    const ushort* __restrict__ q_ws, const ushort* __restrict__ v_ws,
    const float* __restrict__ amask, float* __restrict__ out) {
    const int t = blockIdx.x, h = blockIdx.y, b = blockIdx.z;

    __shared__ ushort KwPl[16384];   // Kw 256x64 (swz) -> later P-half 128x128 (swz)
    __shared__ ushort VtS[16384];    // V^T 64x256 (swz) -> later ctxp 128x64 fp32 (swz)
    __shared__ float  Sstr[128][17]; // strided scores -> probs
    __shared__ float  amw[256];      // window slice of attention_mask

    const int tid = threadIdx.x;     // 0..511
    const int wid = tid >> 6, lane = tid & 63;
    const int quad = lane >> 4, l16 = lane & 15;
    const int r0 = wid * 16;
    const size_t qbase = ((size_t)b * 16 + h) * 2048 * 64;
    const int base_row = (t - 1) * 128;
    const int nk = (t >= 2) ? (t - 1) : 0;

    // ---- stage ----
    if (tid < 256) {
        int j = base_row + tid; if (j < 0) j = 0;
        amw[tid] = amask[(size_t)b * 2048 + j];
    }
#pragma unroll
    for (int i = 0; i < 4; ++i) {
        int u = tid + i * 512;               // 256 rows x 8 chunks
        int row = u >> 3, c = u & 7;
        int jg = base_row + row; if (jg < 0) jg = 0;
        *(uint4*)&KwPl[row * 64 + ((c ^ (row & 7)) * 8)] =
            *(const uint4*)(q_ws + qbase + (size_t)jg * 64 + c * 8);
    }
    {   // Vt[d][j], swizzled: phys = d*256 + ((c ^ (d&7))*8) + (j&7)
        int j = tid & 255, dh0 = (tid >> 8) * 32;
        int jg = base_row + j; if (jg < 0) jg = 0;
        const ushort* src = v_ws + qbase + (size_t)jg * 64 + dh0;
        int cj = j >> 3, j7 = j & 7;
#pragma unroll
        for (int d = 0; d < 32; d += 8) {
            union { uint4 v; ushort u[8]; } tmp;
            tmp.v = *(const uint4*)(src + d);
#pragma unroll
            for (int jj = 0; jj < 8; ++jj) {
                int dd = dh0 + d + jj;
                VtS[dd * 256 + ((cj ^ (dd & 7)) * 8) + j7] = tmp.u[jj];
            }
        }
    }
    __syncthreads();

    // ---- QK^T: wave -> rows [r0,r0+16) x 256 cols ----
    float4v sacc[16] = {};
#pragma unroll
    for (int ks = 0; ks < 2; ++ks) {
        int c = ks * 4 + quad;
        int sw = (c ^ (l16 & 7)) * 8;
        short8 af = *(const short8*)&KwPl[(128 + r0 + l16) * 64 + sw];
#pragma unroll
        for (int nt = 0; nt < 16; ++nt) {
            short8 bfr = *(const short8*)&KwPl[(nt * 16 + l16) * 64 + sw];
            sacc[nt] = __builtin_amdgcn_mfma_f32_16x16x32_bf16(af, bfr, sacc[nt], 0, 0, 0);
        }
    }

    // ---- strided scores: 4 lanes/row, 16-d quarters ----
    const int sr = tid >> 2;             // 0..127
    const int dq = (tid & 3) * 16;
    if (nk > 0) {
        float qv[16];
#pragma unroll
        for (int cc = 0; cc < 2; ++cc) {
            int c = (dq >> 3) + cc;
            union { uint4 v; ushort u[8]; } tm;
            tm.v = *(const uint4*)&KwPl[(128 + sr) * 64 + ((c ^ (sr & 7)) * 8)];
#pragma unroll
            for (int jj = 0; jj < 8; ++jj) qv[cc * 8 + jj] = bf2f(tm.u[jj]);
        }
        for (int k = 0; k < nk; ++k) {
            const ushort* kr = q_ws + qbase + (size_t)(sr + (k << 7)) * 64 + dq;
            float p = 0.f;
#pragma unroll
            for (int d = 0; d < 16; d += 8) {
                union { uint4 v; ushort u[8]; } tm;
                tm.v = *(const uint4*)(kr + d);
#pragma unroll
                for (int jj = 0; jj < 8; ++jj) p += qv[d + jj] * bf2f(tm.u[jj]);
            }
            p += __shfl_xor(p, 1);
            p += __shfl_xor(p, 2);
            if ((tid & 3) == 0)
                Sstr[sr][k] = p * 0.125f + amask[(size_t)b * 2048 + sr + (k << 7)];
        }
    }
    __syncthreads();   // Kw dead; region becomes P-half

    // ---- softmax; write P-half1 (cols 0..127), stash half2 in regs ----
    unsigned pb[4][4];
#pragma unroll
    for (int reg = 0; reg < 4; ++reg) {
        int rr = r0 + quad * 4 + reg;
        float sv[16];
#pragma unroll
        for (int nt = 0; nt < 16; ++nt) {
            int c = nt * 16 + l16;
            bool allowed = (c >= rr) && (c <= rr + 128) && (t > 0 || c >= 128);
            sv[nt] = allowed ? sacc[nt][reg] * 0.125f + amw[c] : -INFINITY;
        }
        float sstr_v = (l16 < nk) ? Sstr[rr][l16] : -INFINITY;
        float m = sstr_v;
#pragma unroll
        for (int nt = 0; nt < 16; ++nt) m = fmaxf(m, sv[nt]);
#pragma unroll
        for (int off = 1; off < 16; off <<= 1) m = fmaxf(m, __shfl_xor(m, off));

        float es = (l16 < nk) ? __expf(sstr_v - m) : 0.f;
        float sum = es;
#pragma unroll
        for (int nt = 0; nt < 16; ++nt) {
            float e = (sv[nt] == -INFINITY) ? 0.f : __expf(sv[nt] - m);
            sv[nt] = e; sum += e;
        }
#pragma unroll
        for (int off = 1; off < 16; off <<= 1) sum += __shfl_xor(sum, off);
        float rden = 1.f / sum;
        // half1 -> LDS (P layout: phys = rr*128 + ((c ^ (rr&15))*8) + (j&7))
#pragma unroll
        for (int nt = 0; nt < 8; ++nt) {
            int c = nt * 2 + (l16 >> 3);
            KwPl[rr * 128 + ((c ^ (rr & 15)) * 8) + (l16 & 7)] = f2bf(sv[nt] * rden);
        }
        // half2 -> packed regs
#pragma unroll
        for (int i2 = 0; i2 < 4; ++i2) {
            unsigned lo = f2bf(sv[8 + 2 * i2] * rden);
            unsigned hi = f2bf(sv[9 + 2 * i2] * rden);
            pb[reg][i2] = lo | (hi << 16);
        }
        if (l16 < nk) Sstr[rr][l16] = es * rden;
    }
    __syncthreads();

    // ---- PV pass 1: P(cols 0..127) x Vt(j 0..127) ----
    float4v cacc[4] = {};
#pragma unroll
    for (int ks = 0; ks < 4; ++ks) {
        int cp = ks * 4 + quad;                       // P chunk 0..15
        short8 af = *(const short8*)&KwPl[(r0 + l16) * 128 + ((cp ^ l16) * 8)];
#pragma unroll
        for (int nt = 0; nt < 4; ++nt) {
            int sw = (cp ^ (l16 & 7)) * 8;            // Vt chunk 0..15
            short8 bfr = *(const short8*)&VtS[(nt * 16 + l16) * 256 + sw];
            cacc[nt] = __builtin_amdgcn_mfma_f32_16x16x32_bf16(af, bfr, cacc[nt], 0, 0, 0);
        }
    }
    __syncthreads();   // P-half1 reads done

    // ---- write P-half2 ----
#pragma unroll
    for (int reg = 0; reg < 4; ++reg) {
        int rr = r0 + quad * 4 + reg;
#pragma unroll
        for (int i2 = 0; i2 < 4; ++i2) {
            int nt0 = 8 + 2 * i2;
#pragma unroll
            for (int e2 = 0; e2 < 2; ++e2) {
                int nt = nt0 + e2;
                int c = (nt - 8) * 2 + (l16 >> 3);    // chunk 0..15 within half
                ushort val = (ushort)((pb[reg][i2] >> (16 * e2)) & 0xFFFF);
                KwPl[rr * 128 + ((c ^ (rr & 15)) * 8) + (l16 & 7)] = val;
            }
        }
    }
    __syncthreads();

    // ---- PV pass 2: P(cols 128..255) x Vt(j 128..255) ----
#pragma unroll
    for (int ks = 0; ks < 4; ++ks) {
        int cp = ks * 4 + quad;                       // chunk within half
        short8 af = *(const short8*)&KwPl[(r0 + l16) * 128 + ((cp ^ l16) * 8)];
#pragma unroll
        for (int nt = 0; nt < 4; ++nt) {
            int cv = 16 + cp;                         // Vt chunk 16..31
            int sw = (cv ^ (l16 & 7)) * 8;
            short8 bfr = *(const short8*)&VtS[(nt * 16 + l16) * 256 + sw];
            cacc[nt] = __builtin_amdgcn_mfma_f32_16x16x32_bf16(af, bfr, cacc[nt], 0, 0, 0);
        }
    }
    __syncthreads();   // Vt reads done; region becomes ctxp

    // ---- strided PV: 4 lanes/row, 16-d quarters -> ctxp (alias Vt) ----
    float* ctxp = (float*)&VtS[0];   // [128][64] fp32, chunk-swizzled
    {
        float acc16[16] = {};
        for (int k = 0; k < nk; ++k) {
            float p = Sstr[sr][k];
            const ushort* vr = v_ws + qbase + (size_t)(sr + (k << 7)) * 64 + dq;
#pragma unroll
            for (int d = 0; d < 16; d += 8) {
                union { uint4 v; ushort u[8]; } tm;
                tm.v = *(const uint4*)(vr + d);
#pragma unroll
                for (int jj = 0; jj < 8; ++jj) acc16[d + jj] += p * bf2f(tm.u[jj]);
            }
        }
#pragma unroll
        for (int d4 = 0; d4 < 4; ++d4) {
            int c = (dq >> 2) + d4;                   // float-chunk 0..15
            *(float4v*)&ctxp[sr * 64 + ((c ^ (sr & 15)) * 4)] =
                *(const float4v*)&acc16[d4 * 4];
        }
    }
    __syncthreads();

    // ---- epilogue: out[b][s][h*64+d], fp32 ----
    const size_t obase = ((size_t)b * 2048 + (size_t)t * 128) * 1024 + (size_t)h * 64;
#pragma unroll
    for (int nt = 0; nt < 4; ++nt)
#pragma unroll
        for (int reg = 0; reg < 4; ++reg) {
            int rr = r0 + quad * 4 + reg;
            int d = nt * 16 + l16;
            float cstr = ctxp[rr * 64 + (((d >> 2) ^ (rr & 15)) * 4) + (d & 3)];
            out[obase + (size_t)rr * 1024 + d] = cacc[nt][reg] + cstr;
        }
}

// ---------------------------------------------------------------------------
extern "C" void kernel_launch(void* const* d_in, const int* in_sizes, int n_in,
                              void* d_out, int out_size, void* d_ws, size_t ws_size,
                              hipStream_t stream) {
    int ihs = -1, iam = -1, iw1 = -1, iw2 = -1, ib1 = -1, ib2 = -1;
    for (int i = 0; i < n_in; ++i) {
        int s = in_sizes[i];
        if      (s == 4194304) { if (ihs < 0) ihs = i; }
        else if (s == 4096)    { if (iam < 0) iam = i; }
        else if (s == 1048576) { if (iw1 < 0) iw1 = i; else if (iw2 < 0) iw2 = i; }
        else if (s == 1024)    { if (ib1 < 0) ib1 = i; else if (ib2 < 0) ib2 = i; }
    }
    if (ihs < 0) ihs = 0; if (iam < 0) iam = 1;
    if (iw1 < 0) iw1 = 2; if (ib1 < 0) ib1 = 3;
    if (iw2 < 0) iw2 = 4; if (ib2 < 0) ib2 = 5;

    const float* hs    = (const float*)d_in[ihs];
    const float* amask = (const float*)d_in[iam];
    const float* Wq    = (const float*)d_in[iw1];
    const float* bq    = (const float*)d_in[ib1];
    const float* Wv    = (const float*)d_in[iw2];
    const float* bv    = (const float*)d_in[ib2];
    float* out = (float*)d_out;

    char* ws = (char*)d_ws;
    ushort* Wtq  = (ushort*)(ws);                           // 2 MB
    ushort* Wtv  = (ushort*)(ws + (1u << 21));              // 2 MB
    ushort* hsb  = (ushort*)(ws + (2u << 21));              // 8 MB
    ushort* q_ws = (ushort*)(ws + (2u << 21) + (1u << 23)); // 8 MB
    ushort* v_ws = (ushort*)(ws + (2u << 21) + (2u << 23)); // 8 MB

    convert_hs<<<1024, 256, 0, stream>>>(hs, hsb);
    transpose_w<<<dim3(16, 16, 2), 256, 0, stream>>>(Wq, Wv, Wtq, Wtv);
    qv_gemm<<<dim3(8, 32, 2), 256, 0, stream>>>(hsb, Wtq, Wtv, bq, bv, q_ws, v_ws);
    attn<<<dim3(16, 16, 2), 512, 0, stream>>>(q_ws, v_ws, amask, out);
}